// Round 4
// baseline (471.452 us; speedup 1.0000x reference)
//
#include <hip/hip_runtime.h>
#include <cmath>

#define N_ENT 100000
#define EHALF 1000000
#define N_REL 500
#define NBUK 196          // ceil(100000/512) coarse dst-buckets
#define DPB 512           // dsts per bucket (dst>>9)

#ifndef M_PI
#define M_PI 3.14159265358979323846
#endif

typedef _Float16 f16x8 __attribute__((ext_vector_type(8)));
typedef _Float16 f16x2 __attribute__((ext_vector_type(2)));
typedef float f32x4 __attribute__((ext_vector_type(4)));

// ---------------- DFT tables ----------------
// Spectrum layout per row (128): slot0=Re(bin0), slot1=Re(bin64),
// slot 2f=Re(bin f), slot 2f+1=Im(bin f), f=1..63.
__global__ void k_tabs(float* __restrict__ Ftab, float* __restrict__ Gtab,
                       _Float16* __restrict__ FtabT) {
  int i = blockIdx.x * 256 + threadIdx.x;
  if (i >= 128 * 128) return;
  int n = i >> 7, s = i & 127;
  float fv, gv;
  if (s == 0) { fv = 1.f; gv = 1.f / 384.f; }
  else if (s == 1) { float sg = (n & 1) ? -1.f : 1.f; fv = sg; gv = sg / 384.f; }
  else {
    int f = s >> 1;
    double ang = 2.0 * M_PI * (double)((f * n) & 127) / 128.0;
    if (!(s & 1)) { double c = cos(ang); fv = (float)c; gv = (float)(c * (2.0 / 384.0)); }
    else { double sv = sin(ang); fv = (float)(-sv); gv = (float)(-sv * (2.0 / 384.0)); }
  }
  Ftab[n * 128 + s] = fv;
  Gtab[s * 128 + n] = gv;
  FtabT[s * 128 + n] = (_Float16)fv;
}

__global__ void k_dftrel(const float* __restrict__ rel, const float* __restrict__ looprel,
                         const float* __restrict__ Ftab, float* __restrict__ Rf) {
  int r = blockIdx.x, s = threadIdx.x;
  const float* row = (r < N_REL) ? rel + (size_t)r * 128 : looprel;
  float acc = 0.f;
  for (int n = 0; n < 128; ++n) acc += row[n] * Ftab[n * 128 + s];
  Rf[(size_t)r * 128 + s] = acc;
}

__global__ void k_rotloop(float* __restrict__ Wl, const float* __restrict__ Rfl) {
  int c = threadIdx.x;
  int f = blockIdx.x;
  if (f == 0) {
    Wl[c]       = Rfl[0] * Wl[c];
    Wl[128 + c] = Rfl[1] * Wl[128 + c];
  } else {
    float rr = Rfl[2 * f], ri = Rfl[2 * f + 1];
    float a = Wl[2 * f * 128 + c], b = Wl[(2 * f + 1) * 128 + c];
    Wl[2 * f * 128 + c]       = rr * a + ri * b;
    Wl[(2 * f + 1) * 128 + c] = ri * a - rr * b;
  }
}

__global__ void k_wt(const float* __restrict__ W, _Float16* __restrict__ WT, int K) {
  int i = blockIdx.x * 256 + threadIdx.x;
  if (i >= K * 128) return;
  int k = i >> 7, c = i & 127;
  WT[(size_t)c * K + k] = (_Float16)W[i];
}

// ---------------- fp32 GEMM (small preps + rel_out), N fixed = 128 ----------------
__global__ __launch_bounds__(256) void gemm128(
    const float* __restrict__ A, int lda,
    const float* __restrict__ B,
    float* __restrict__ C, int ldc,
    int M, int K) {
  __shared__ float As[64][64];
  __shared__ float Bs[64][128];
  const int t = threadIdx.x;
  const int m0 = blockIdx.x * 64;
  const int cg = t & 31;
  const int eg = t >> 5;
  float acc[8][4];
#pragma unroll
  for (int i = 0; i < 8; ++i)
#pragma unroll
    for (int j = 0; j < 4; ++j) acc[i][j] = 0.f;

  for (int k0 = 0; k0 < K; k0 += 64) {
#pragma unroll
    for (int p = 0; p < 4; ++p) {
      int idx = t + p * 256;
      int r = idx >> 4, c4 = idx & 15;
      int gr = m0 + r;
      float4 v = make_float4(0.f, 0.f, 0.f, 0.f);
      if (gr < M) v = *(const float4*)(A + (size_t)gr * lda + k0 + c4 * 4);
      *(float4*)&As[r][c4 * 4] = v;
    }
#pragma unroll
    for (int p = 0; p < 8; ++p) {
      int idx = t + p * 256;
      int r = idx >> 5, c4 = idx & 31;
      float4 v = *(const float4*)(B + (size_t)(k0 + r) * 128 + c4 * 4);
      *(float4*)&Bs[r][c4 * 4] = v;
    }
    __syncthreads();
#pragma unroll
    for (int k = 0; k < 64; ++k) {
      float4 bv = *(float4*)&Bs[k][cg * 4];
#pragma unroll
      for (int i = 0; i < 8; ++i) {
        float av = As[eg * 8 + i][k];
        acc[i][0] += av * bv.x; acc[i][1] += av * bv.y;
        acc[i][2] += av * bv.z; acc[i][3] += av * bv.w;
      }
    }
    __syncthreads();
  }
#pragma unroll
  for (int i = 0; i < 8; ++i) {
    int gr = m0 + eg * 8 + i;
    if (gr < M) {
      float4 v = make_float4(acc[i][0], acc[i][1], acc[i][2], acc[i][3]);
      *(float4*)(C + (size_t)gr * ldc + cg * 4) = v;
    }
  }
}

// ---------------- f16 MFMA GEMM, N=128 ----------------
__device__ inline f16x8 loadAfrag(const _Float16* A, size_t off) {
  return *(const f16x8*)(A + off);
}
__device__ inline f16x8 loadAfrag(const float* A, size_t off) {
  float4 u = *(const float4*)(A + off);
  float4 v = *(const float4*)(A + off + 4);
  return (f16x8){(_Float16)u.x, (_Float16)u.y, (_Float16)u.z, (_Float16)u.w,
                 (_Float16)v.x, (_Float16)v.y, (_Float16)v.z, (_Float16)v.w};
}

// MODE 0: fp32 C (+bias, +BN stats). MODE 1: f16 C (ldc) + scaled copies
// XinS = dinvIn[row]*val, XoutS = dinvOut[row]*val (both [M][128]).
template<int K, int KS, int MODE, bool BN, typename AT>
__global__ __launch_bounds__(256) void mgemm(
    const AT* __restrict__ A, int lda,
    const _Float16* __restrict__ BT,
    void* __restrict__ Cv, int ldc, int M,
    const float* __restrict__ bias, float* __restrict__ bnAcc,
    const float* __restrict__ dvIn, const float* __restrict__ dvOut,
    _Float16* __restrict__ XinS, _Float16* __restrict__ XoutS) {
  __shared__ __align__(16) char lds[128 * KS * 2 + 4096];
  const int t = threadIdx.x;
  const int l = t & 63, w = t >> 6;
  const int col0 = l & 15, rg = l >> 4;
  const int rowbase = blockIdx.x * 256 + w * 64;
  const int sw = (col0 & 7) << 4;

  f32x4 acc[4][8];
  f32x4 zz = {0.f, 0.f, 0.f, 0.f};
#pragma unroll
  for (int a = 0; a < 4; ++a)
#pragma unroll
    for (int n = 0; n < 8; ++n) acc[a][n] = zz;

  for (int ks0 = 0; ks0 < K; ks0 += KS) {
    __syncthreads();
    const int CH = KS / 8;
    for (int u = t; u < 128 * CH; u += 256) {
      int col = u / CH, kc = u % CH;
      f16x8 vch = *(const f16x8*)(BT + (size_t)col * K + ks0 + kc * 8);
      *(f16x8*)(lds + col * (KS * 2) + ((kc * 16) ^ ((col & 7) << 4))) = vch;
    }
    __syncthreads();
#pragma unroll
    for (int ks = 0; ks < KS / 32; ++ks) {
      int kb = ks0 + ks * 32 + rg * 8;
      f16x8 af[4];
#pragma unroll
      for (int a = 0; a < 4; ++a) {
        int rb = rowbase + a * 16;
        if (rb < M) af[a] = loadAfrag(A, (size_t)(rb + col0) * lda + kb);
        else af[a] = (f16x8){0, 0, 0, 0, 0, 0, 0, 0};
      }
      int kc = ks * 4 + rg;
#pragma unroll
      for (int n = 0; n < 8; ++n) {
        f16x8 bf = *(const f16x8*)(lds + (n * 16 + col0) * (KS * 2) + ((kc * 16) ^ sw));
#pragma unroll
        for (int a = 0; a < 4; ++a)
          acc[a][n] = __builtin_amdgcn_mfma_f32_16x16x32_f16(af[a], bf, acc[a][n], 0, 0, 0);
      }
    }
  }

  if (MODE == 1) {
    _Float16* C = (_Float16*)Cv;
#pragma unroll
    for (int a = 0; a < 4; ++a) {
      int rb = rowbase + a * 16;
      if (rb >= M) continue;
#pragma unroll
      for (int r = 0; r < 4; ++r) {
        int row = rb + rg * 4 + r;
        float dIn = dvIn[row], dOut = dvOut[row];
#pragma unroll
        for (int n = 0; n < 8; ++n) {
          int col = n * 16 + col0;
          float val = acc[a][n][r];
          C[(size_t)row * ldc + col] = (_Float16)val;
          XinS[(size_t)row * 128 + col] = (_Float16)(val * dIn);
          XoutS[(size_t)row * 128 + col] = (_Float16)(val * dOut);
        }
      }
    }
  } else {
    float* C = (float*)Cv;
    float sacc[8], qacc[8];
#pragma unroll
    for (int n = 0; n < 8; ++n) { sacc[n] = 0.f; qacc[n] = 0.f; }
#pragma unroll
    for (int a = 0; a < 4; ++a) {
      int rb = rowbase + a * 16;
      if (rb >= M) continue;
#pragma unroll
      for (int n = 0; n < 8; ++n) {
        int col = n * 16 + col0;
        float bi = bias ? bias[col] : 0.f;
#pragma unroll
        for (int r = 0; r < 4; ++r) {
          float val = acc[a][n][r] + bi;
          C[(size_t)(rb + rg * 4 + r) * ldc + col] = val;
          if (BN) { sacc[n] += val; qacc[n] += val * val; }
        }
      }
    }
    if (BN) {
      __syncthreads();
      float* Sb = (float*)lds;
      float* Qb = Sb + 512;
#pragma unroll
      for (int n = 0; n < 8; ++n) {
        float s = sacc[n], q = qacc[n];
        s += __shfl_xor(s, 16); s += __shfl_xor(s, 32);
        q += __shfl_xor(q, 16); q += __shfl_xor(q, 32);
        if (rg == 0) { Sb[w * 128 + n * 16 + col0] = s; Qb[w * 128 + n * 16 + col0] = q; }
      }
      __syncthreads();
      if (t < 128) {
        float s = Sb[t] + Sb[128 + t] + Sb[256 + t] + Sb[384 + t];
        float q = Qb[t] + Qb[128 + t] + Qb[256 + t] + Qb[384 + t];
        atomicAdd(&bnAcc[t], s);
        atomicAdd(&bnAcc[128 + t], q);
      }
    }
  }
}

// ---------------- edge preprocessing ----------------
__global__ __launch_bounds__(256) void k_hist(const int* __restrict__ ei,
                       int* __restrict__ degIn, int* __restrict__ degOut,
                       int* __restrict__ bcntIn, int* __restrict__ bcntOut) {
  __shared__ int lbIn[NBUK], lbOut[NBUK];
  int t = threadIdx.x;
  if (t < NBUK) { lbIn[t] = 0; lbOut[t] = 0; }
  __syncthreads();
  int stride = gridDim.x * 256;
  for (int e = blockIdx.x * 256 + t; e < EHALF; e += stride) {
    atomicAdd(&degIn[ei[e]], 1);
    atomicAdd(&degOut[ei[EHALF + e]], 1);
    atomicAdd(&lbIn[ei[2 * EHALF + e] >> 9], 1);
    atomicAdd(&lbOut[ei[3 * EHALF + e] >> 9], 1);
  }
  __syncthreads();
  if (t < NBUK) {
    atomicAdd(&bcntIn[t], lbIn[t]);
    atomicAdd(&bcntOut[t], lbOut[t]);
  }
}

__global__ void k_dinv2(const int* __restrict__ degIn, const int* __restrict__ degOut,
                        float* __restrict__ dinvIn, float* __restrict__ dinvOut) {
  int i = blockIdx.x * 256 + threadIdx.x;
  if (i < N_ENT) {
    int d = degIn[i];
    dinvIn[i] = (d > 0) ? rsqrtf((float)d) : 0.f;
  } else if (i < 2 * N_ENT) {
    int j = i - N_ENT;
    int d = degOut[j];
    dinvOut[j] = (d > 0) ? rsqrtf((float)d) : 0.f;
  }
}

__global__ void k_bscan(const int* __restrict__ bcntIn, const int* __restrict__ bcntOut,
                        int* __restrict__ boffIn, int* __restrict__ gcurIn, int* __restrict__ csrBIn,
                        int* __restrict__ boffOut, int* __restrict__ gcurOut, int* __restrict__ csrBOut,
                        int* __restrict__ offFineIn, int* __restrict__ offFineOut) {
  __shared__ int sp[256], se[256];
  int t = threadIdx.x;
  for (int dir = 0; dir < 2; ++dir) {
    const int* bc = dir ? bcntOut : bcntIn;
    int c = (t < NBUK) ? bc[t] : 0;
    int pv = (t < NBUK) ? ((c + 771) & ~3) : 0;
    sp[t] = pv; se[t] = c;
    __syncthreads();
    for (int o = 1; o < 256; o <<= 1) {
      int ap = (t >= o) ? sp[t - o] : 0;
      int ae = (t >= o) ? se[t - o] : 0;
      __syncthreads();
      sp[t] += ap; se[t] += ae;
      __syncthreads();
    }
    if (t < NBUK) {
      int exP = sp[t] - pv;
      int exE = se[t] - c;
      if (dir) { boffOut[t] = exP; gcurOut[t] = exP; csrBOut[t] = exE; }
      else     { boffIn[t]  = exP; gcurIn[t]  = exP; csrBIn[t]  = exE; }
    }
    __syncthreads();
  }
  if (t == 0) { offFineIn[N_ENT] = EHALF; offFineOut[N_ENT] = EHALF; }
}

// coarse split: block-exclusive padded 32B chunks per bucket -> no write amp
__global__ __launch_bounds__(256) void k_split(
    const int* __restrict__ srcA, const int* __restrict__ dstA, const int* __restrict__ typA,
    int* __restrict__ gcur, uint2* __restrict__ rec) {
  __shared__ int bcnt[NBUK], cnt2[NBUK], base[NBUK], nn[NBUK];
  const int t = threadIdx.x;
  const int SPAN = 3907;
  int st = blockIdx.x * SPAN;
  int en = min(st + SPAN, EHALF);
  if (t < NBUK) { bcnt[t] = 0; cnt2[t] = 0; }
  __syncthreads();
  unsigned w0[16], w1[16]; int bb[16];
#pragma unroll
  for (int j = 0; j < 16; ++j) {
    int e = st + j * 256 + t;
    bb[j] = -1;
    if (e < en) {
      int s = srcA[e], d = dstA[e], ty = typA[e];
      w0[j] = (unsigned)s | ((unsigned)ty << 17);
      w1[j] = (unsigned)(d & 511) | 0x80000000u;
      int b = d >> 9;
      bb[j] = b;
      atomicAdd(&bcnt[b], 1);
    }
  }
  __syncthreads();
  if (t < NBUK) {
    int n = bcnt[t]; nn[t] = n;
    base[t] = n ? atomicAdd(&gcur[t], (n + 3) & ~3) : 0;
  }
  __syncthreads();
#pragma unroll
  for (int j = 0; j < 16; ++j) {
    if (bb[j] >= 0) {
      int p = atomicAdd(&cnt2[bb[j]], 1);
      rec[(size_t)base[bb[j]] + p] = make_uint2(w0[j], w1[j]);
    }
  }
  __syncthreads();
  if (t < NBUK) {
    int n = nn[t];
    if (n & 3) {
      int pe = (n + 3) & ~3;
      for (int k = n; k < pe; ++k) rec[(size_t)base[t] + k] = make_uint2(0u, 0u);
    }
  }
}

// fine sort within bucket -> dense CSR of {xoff, roff} byte-offset records
__global__ __launch_bounds__(512) void k_fsort(
    const uint2* __restrict__ recIn, const int* __restrict__ boffIn, const int* __restrict__ gcurIn,
    const int* __restrict__ csrBIn, uint2* __restrict__ csrIn, int* __restrict__ offFineIn,
    const uint2* __restrict__ recOut, const int* __restrict__ boffOut, const int* __restrict__ gcurOut,
    const int* __restrict__ csrBOut, uint2* __restrict__ csrOut, int* __restrict__ offFineOut) {
  int b = blockIdx.x % NBUK;
  int dir = blockIdx.x / NBUK;
  const uint2* rec = dir ? recOut : recIn;
  const int gs = (dir ? boffOut : boffIn)[b];
  const int ge = (dir ? gcurOut : gcurIn)[b];
  const int cbase = (dir ? csrBOut : csrBIn)[b];
  uint2* csr = dir ? csrOut : csrIn;
  int* offF = dir ? offFineOut : offFineIn;
  __shared__ int h[DPB], sc[DPB], c2[DPB];
  int t = threadIdx.x;
  h[t] = 0; c2[t] = 0;
  __syncthreads();
  for (int i = gs + t; i < ge; i += 512) {
    uint2 r = rec[i];
    if (r.y >> 31) atomicAdd(&h[r.y & 511], 1);
  }
  __syncthreads();
  sc[t] = h[t];
  __syncthreads();
  for (int o = 1; o < 512; o <<= 1) {
    int a = (t >= o) ? sc[t - o] : 0;
    __syncthreads();
    sc[t] += a;
    __syncthreads();
  }
  int excl = sc[t] - h[t];
  int dst = b * 512 + t;
  if (dst < N_ENT) offF[dst] = cbase + excl;
  __syncthreads();
  sc[t] = excl;
  __syncthreads();
  for (int i = gs + t; i < ge; i += 512) {
    uint2 r = rec[i];
    if (r.y >> 31) {
      int d = r.y & 511;
      int p = atomicAdd(&c2[d], 1);
      csr[(size_t)cbase + sc[d] + p] =
          make_uint2((r.x & 0x1FFFFu) << 8, (r.x >> 17) << 9);
    }
  }
}

// ---------------- frequency-domain edge aggregation (one direction) ----------------
// XS: dinv-prescaled spectra [N_ENT][128] f16. Record: {xoff bytes, roff bytes}.
// Wave per entity, lane l owns complex bin l (lane 0: the two real bins 0/64).
__global__ __launch_bounds__(256) void k_agg2(
    const _Float16* __restrict__ XS, const float* __restrict__ Rf,
    const uint2* __restrict__ csr, const int* __restrict__ offF,
    const float* __restrict__ dinvD, _Float16* __restrict__ Aout) {
  int w = threadIdx.x >> 6, l = threadIdx.x & 63;
  int v = blockIdx.x * 4 + w;
  if (v >= N_ENT) return;
  const char* Xb = (const char*)XS;
  const char* Rb = (const char*)Rf;
  const unsigned lx = (unsigned)l * 4u;
  const unsigned lr = (unsigned)l * 8u;
  const bool l0 = (l == 0);
  int b = offF[v], e = offF[v + 1];
  float dv = dinvD[v];
  float ax = 0.f, ay = 0.f;
  int i = b;
  for (; i + 2 <= e; i += 2) {
    uint2 q0 = csr[i], q1 = csr[i + 1];
    f16x2 x0 = *(const f16x2*)(Xb + q0.x + lx);
    float2 r0 = *(const float2*)(Rb + q0.y + lr);
    f16x2 x1 = *(const f16x2*)(Xb + q1.x + lx);
    float2 r1 = *(const float2*)(Rb + q1.y + lr);
    float x0r = (float)x0[0], x0i = (float)x0[1];
    float x1r = (float)x1[0], x1i = (float)x1[1];
    float b0 = l0 ? 0.f : r0.y;
    float d0 = l0 ? r0.y : -r0.x;
    float b1 = l0 ? 0.f : r1.y;
    float d1 = l0 ? r1.y : -r1.x;
    ax = fmaf(x0r, r0.x, ax); ax = fmaf(x0i, b0, ax);
    ay = fmaf(x0r, b0, ay);   ay = fmaf(x0i, d0, ay);
    ax = fmaf(x1r, r1.x, ax); ax = fmaf(x1i, b1, ax);
    ay = fmaf(x1r, b1, ay);   ay = fmaf(x1i, d1, ay);
  }
  if (i < e) {
    uint2 q0 = csr[i];
    f16x2 x0 = *(const f16x2*)(Xb + q0.x + lx);
    float2 r0 = *(const float2*)(Rb + q0.y + lr);
    float x0r = (float)x0[0], x0i = (float)x0[1];
    float b0 = l0 ? 0.f : r0.y;
    float d0 = l0 ? r0.y : -r0.x;
    ax = fmaf(x0r, r0.x, ax); ax = fmaf(x0i, b0, ax);
    ay = fmaf(x0r, b0, ay);   ay = fmaf(x0i, d0, ay);
  }
  *(f16x2*)(Aout + (size_t)v * 384 + 2 * l) = (f16x2){(_Float16)(ax * dv), (_Float16)(ay * dv)};
}

// ---------------- batch norm ----------------
__global__ void k_bnfin(const float* __restrict__ bnAcc, const float* __restrict__ bnw,
                        const float* __restrict__ bnb, float* __restrict__ ss) {
  int c = threadIdx.x;
  float mu = bnAcc[c] * (1.f / (float)N_ENT);
  float var = bnAcc[128 + c] * (1.f / (float)N_ENT) - mu * mu;
  float sc = bnw[c] * rsqrtf(var + 1e-5f);
  ss[c] = sc; ss[128 + c] = bnb[c] - mu * sc;
}

__global__ void k_norm(float* __restrict__ out, const float* __restrict__ ss) {
  int i = blockIdx.x * 256 + threadIdx.x;
  float4* o = (float4*)out;
  float4 v = o[i];
  int c = (i & 31) * 4;
  v.x = v.x * ss[c]     + ss[128 + c];
  v.y = v.y * ss[c + 1] + ss[129 + c];
  v.z = v.z * ss[c + 2] + ss[130 + c];
  v.w = v.w * ss[c + 3] + ss[131 + c];
  o[i] = v;
}

extern "C" void kernel_launch(void* const* d_in, const int* in_sizes, int n_in,
                              void* d_out, int out_size, void* d_ws, size_t ws_size,
                              hipStream_t stream) {
  const float* x       = (const float*)d_in[0];
  const float* rel     = (const float*)d_in[1];
  const float* w_in    = (const float*)d_in[2];
  const float* w_out   = (const float*)d_in[3];
  const float* w_loop  = (const float*)d_in[4];
  const float* w_rel   = (const float*)d_in[5];
  const float* looprel = (const float*)d_in[6];
  const float* bias    = (const float*)d_in[7];
  const float* bnw     = (const float*)d_in[8];
  const float* bnb     = (const float*)d_in[9];
  const int*   ei      = (const int*)d_in[10];
  const int*   et      = (const int*)d_in[11];
  float* out = (float*)d_out;

  char* p = (char*)d_ws;
  auto alloc = [&](size_t bytes) -> void* {
    void* r = (void*)p;
    p += (bytes + 255) & ~(size_t)255;
    return r;
  };
  const size_t RECCAP = EHALF + NBUK * 776;
  _Float16* Abuf  = (_Float16*)alloc((size_t)N_ENT * 384 * 2);
  _Float16* XinS  = (_Float16*)alloc((size_t)N_ENT * 128 * 2);
  _Float16* XoutS = (_Float16*)alloc((size_t)N_ENT * 128 * 2);
  _Float16* WT    = (_Float16*)alloc(128 * 384 * 2);
  _Float16* FtabT = (_Float16*)alloc(128 * 128 * 2);
  float* Wstack   = (float*)alloc(384 * 128 * 4);
  float* Ftab     = (float*)alloc(128 * 128 * 4);
  float* Gtab     = (float*)alloc(128 * 128 * 4);
  float* Rf       = (float*)alloc(501 * 128 * 4);
  int*   degIn    = (int*)alloc(N_ENT * 4);
  int*   degOut   = (int*)alloc(N_ENT * 4);
  float* dinvIn   = (float*)alloc(N_ENT * 4);
  float* dinvOut  = (float*)alloc(N_ENT * 4);
  int*   bcntIn   = (int*)alloc(NBUK * 4);
  int*   bcntOut  = (int*)alloc(NBUK * 4);
  int*   boffIn   = (int*)alloc(NBUK * 4);
  int*   boffOut  = (int*)alloc(NBUK * 4);
  int*   gcurIn   = (int*)alloc(NBUK * 4);
  int*   gcurOut  = (int*)alloc(NBUK * 4);
  int*   csrBIn   = (int*)alloc((NBUK + 1) * 4);
  int*   csrBOut  = (int*)alloc((NBUK + 1) * 4);
  int*   offFineIn  = (int*)alloc((N_ENT + 1) * 4);
  int*   offFineOut = (int*)alloc((N_ENT + 1) * 4);
  uint2* recInC   = (uint2*)alloc(RECCAP * 8);
  uint2* recOutC  = (uint2*)alloc(RECCAP * 8);
  uint2* csrIn    = (uint2*)alloc((size_t)EHALF * 8);
  uint2* csrOut   = (uint2*)alloc((size_t)EHALF * 8);
  float* bnAcc    = (float*)alloc(256 * 4);
  float* ss       = (float*)alloc(256 * 4);

  hipMemsetAsync(degIn, 0, N_ENT * 4, stream);
  hipMemsetAsync(degOut, 0, N_ENT * 4, stream);
  hipMemsetAsync(bcntIn, 0, NBUK * 4, stream);
  hipMemsetAsync(bcntOut, 0, NBUK * 4, stream);
  hipMemsetAsync(bnAcc, 0, 256 * 4, stream);

  // tables + relation spectra + folded weight stack
  k_tabs<<<64, 256, 0, stream>>>(Ftab, Gtab, FtabT);
  k_dftrel<<<501, 128, 0, stream>>>(rel, looprel, Ftab, Rf);
  gemm128<<<2, 256, 0, stream>>>(Gtab, 128, w_in,   Wstack,             128, 128, 128);
  gemm128<<<2, 256, 0, stream>>>(Gtab, 128, w_out,  Wstack + 128 * 128, 128, 128, 128);
  gemm128<<<2, 256, 0, stream>>>(Gtab, 128, w_loop, Wstack + 256 * 128, 128, 128, 128);
  k_rotloop<<<64, 128, 0, stream>>>(Wstack + 256 * 128, Rf + 500 * 128);
  k_wt<<<192, 256, 0, stream>>>(Wstack, WT, 384);

  // degrees + coarse bucket counts (before Xf gemm: epilogue needs dinv)
  k_hist<<<512, 256, 0, stream>>>(ei, degIn, degOut, bcntIn, bcntOut);
  k_dinv2<<<(2 * N_ENT + 255) / 256, 256, 0, stream>>>(degIn, degOut, dinvIn, dinvOut);
  k_bscan<<<1, 256, 0, stream>>>(bcntIn, bcntOut, boffIn, gcurIn, csrBIn,
                                 boffOut, gcurOut, csrBOut, offFineIn, offFineOut);

  // Xf = rfft(x) via f16 MFMA; epilogue also writes dinv-prescaled copies
  mgemm<128, 128, 1, false, float><<<(N_ENT + 255) / 256, 256, 0, stream>>>(
      x, 128, FtabT, (void*)(Abuf + 256), 384, N_ENT, nullptr, nullptr,
      dinvIn, dinvOut, XinS, XoutS);

  // coarse split (write-amp-free), then fine CSR sort per bucket
  k_split<<<256, 256, 0, stream>>>(ei,         ei + 2 * EHALF, et,         gcurIn,  recInC);
  k_split<<<256, 256, 0, stream>>>(ei + EHALF, ei + 3 * EHALF, et + EHALF, gcurOut, recOutC);
  k_fsort<<<2 * NBUK, 512, 0, stream>>>(recInC, boffIn, gcurIn, csrBIn, csrIn, offFineIn,
                                        recOutC, boffOut, gcurOut, csrBOut, csrOut, offFineOut);

  // frequency-domain aggregation, one pass per direction
  k_agg2<<<N_ENT / 4, 256, 0, stream>>>(XinS, Rf, csrIn, offFineIn, dinvIn, Abuf);
  k_agg2<<<N_ENT / 4, 256, 0, stream>>>(XoutS, Rf, csrOut, offFineOut, dinvOut, Abuf + 128);

  // fused output GEMM (f16 MFMA): [c_in|c_out|Xf] @ Wstack + bias, BN stats
  mgemm<384, 192, 0, true, _Float16><<<(N_ENT + 255) / 256, 256, 0, stream>>>(
      Abuf, 384, WT, (void*)out, 128, N_ENT, bias, bnAcc,
      nullptr, nullptr, nullptr, nullptr);
  k_bnfin<<<1, 128, 0, stream>>>(bnAcc, bnw, bnb, ss);
  k_norm<<<(N_ENT * 128 / 4) / 256, 256, 0, stream>>>(out, ss);

  // rel_out = rel_embed @ w_rel (fp32)
  gemm128<<<(N_REL + 63) / 64, 256, 0, stream>>>(rel, 128, w_rel, out + (size_t)N_ENT * 128, 128, N_REL, 128);
}

// Round 5
// 447.576 us; speedup vs baseline: 1.0533x; 1.0533x over previous
//
#include <hip/hip_runtime.h>
#include <cmath>

#define N_ENT 100000
#define EHALF 1000000
#define N_REL 500
#define NBUK 196          // ceil(100000/512) coarse buckets (key>>9)
#define DPB 512           // entities per bucket
#define CCB 512           // k_ccount blocks

#ifndef M_PI
#define M_PI 3.14159265358979323846
#endif

typedef _Float16 f16x8 __attribute__((ext_vector_type(8)));
typedef _Float16 f16x2 __attribute__((ext_vector_type(2)));
typedef float f32x4 __attribute__((ext_vector_type(4)));

// ---------------- DFT tables ----------------
// Spectrum layout per row (128): slot0=Re(bin0), slot1=Re(bin64),
// slot 2f=Re(bin f), slot 2f+1=Im(bin f), f=1..63.
__global__ void k_tabs(float* __restrict__ Ftab, float* __restrict__ Gtab,
                       _Float16* __restrict__ FtabT) {
  int i = blockIdx.x * 256 + threadIdx.x;
  if (i >= 128 * 128) return;
  int n = i >> 7, s = i & 127;
  float fv, gv;
  if (s == 0) { fv = 1.f; gv = 1.f / 384.f; }
  else if (s == 1) { float sg = (n & 1) ? -1.f : 1.f; fv = sg; gv = sg / 384.f; }
  else {
    int f = s >> 1;
    double ang = 2.0 * M_PI * (double)((f * n) & 127) / 128.0;
    if (!(s & 1)) { double c = cos(ang); fv = (float)c; gv = (float)(c * (2.0 / 384.0)); }
    else { double sv = sin(ang); fv = (float)(-sv); gv = (float)(-sv * (2.0 / 384.0)); }
  }
  Ftab[n * 128 + s] = fv;
  Gtab[s * 128 + n] = gv;
  FtabT[s * 128 + n] = (_Float16)fv;
}

__global__ void k_dftrel(const float* __restrict__ rel, const float* __restrict__ looprel,
                         const float* __restrict__ Ftab, float* __restrict__ Rf) {
  int r = blockIdx.x, s = threadIdx.x;
  const float* row = (r < N_REL) ? rel + (size_t)r * 128 : looprel;
  float acc = 0.f;
  for (int n = 0; n < 128; ++n) acc += row[n] * Ftab[n * 128 + s];
  Rf[(size_t)r * 128 + s] = acc;
}

__global__ void k_rotloop(float* __restrict__ Wl, const float* __restrict__ Rfl) {
  int c = threadIdx.x;
  int f = blockIdx.x;
  if (f == 0) {
    Wl[c]       = Rfl[0] * Wl[c];
    Wl[128 + c] = Rfl[1] * Wl[128 + c];
  } else {
    float rr = Rfl[2 * f], ri = Rfl[2 * f + 1];
    float a = Wl[2 * f * 128 + c], b = Wl[(2 * f + 1) * 128 + c];
    Wl[2 * f * 128 + c]       = rr * a + ri * b;
    Wl[(2 * f + 1) * 128 + c] = ri * a - rr * b;
  }
}

__global__ void k_wt(const float* __restrict__ W, _Float16* __restrict__ WT, int K) {
  int i = blockIdx.x * 256 + threadIdx.x;
  if (i >= K * 128) return;
  int k = i >> 7, c = i & 127;
  WT[(size_t)c * K + k] = (_Float16)W[i];
}

// ---------------- fp32 GEMM (small preps + rel_out), N fixed = 128 ----------------
__global__ __launch_bounds__(256) void gemm128(
    const float* __restrict__ A, int lda,
    const float* __restrict__ B,
    float* __restrict__ C, int ldc,
    int M, int K) {
  __shared__ float As[64][64];
  __shared__ float Bs[64][128];
  const int t = threadIdx.x;
  const int m0 = blockIdx.x * 64;
  const int cg = t & 31;
  const int eg = t >> 5;
  float acc[8][4];
#pragma unroll
  for (int i = 0; i < 8; ++i)
#pragma unroll
    for (int j = 0; j < 4; ++j) acc[i][j] = 0.f;

  for (int k0 = 0; k0 < K; k0 += 64) {
#pragma unroll
    for (int p = 0; p < 4; ++p) {
      int idx = t + p * 256;
      int r = idx >> 4, c4 = idx & 15;
      int gr = m0 + r;
      float4 v = make_float4(0.f, 0.f, 0.f, 0.f);
      if (gr < M) v = *(const float4*)(A + (size_t)gr * lda + k0 + c4 * 4);
      *(float4*)&As[r][c4 * 4] = v;
    }
#pragma unroll
    for (int p = 0; p < 8; ++p) {
      int idx = t + p * 256;
      int r = idx >> 5, c4 = idx & 31;
      float4 v = *(const float4*)(B + (size_t)(k0 + r) * 128 + c4 * 4);
      *(float4*)&Bs[r][c4 * 4] = v;
    }
    __syncthreads();
#pragma unroll
    for (int k = 0; k < 64; ++k) {
      float4 bv = *(float4*)&Bs[k][cg * 4];
#pragma unroll
      for (int i = 0; i < 8; ++i) {
        float av = As[eg * 8 + i][k];
        acc[i][0] += av * bv.x; acc[i][1] += av * bv.y;
        acc[i][2] += av * bv.z; acc[i][3] += av * bv.w;
      }
    }
    __syncthreads();
  }
#pragma unroll
  for (int i = 0; i < 8; ++i) {
    int gr = m0 + eg * 8 + i;
    if (gr < M) {
      float4 v = make_float4(acc[i][0], acc[i][1], acc[i][2], acc[i][3]);
      *(float4*)(C + (size_t)gr * ldc + cg * 4) = v;
    }
  }
}

// ---------------- f16 MFMA GEMM, N=128 ----------------
__device__ inline f16x8 loadAfrag(const _Float16* A, size_t off) {
  return *(const f16x8*)(A + off);
}
__device__ inline f16x8 loadAfrag(const float* A, size_t off) {
  float4 u = *(const float4*)(A + off);
  float4 v = *(const float4*)(A + off + 4);
  return (f16x8){(_Float16)u.x, (_Float16)u.y, (_Float16)u.z, (_Float16)u.w,
                 (_Float16)v.x, (_Float16)v.y, (_Float16)v.z, (_Float16)v.w};
}

// MODE 0: fp32 C (+bias, +BN stats). MODE 1: f16 C (ldc) + dinv-prescaled copies.
template<int K, int KS, int MODE, bool BN, typename AT>
__global__ __launch_bounds__(256) void mgemm(
    const AT* __restrict__ A, int lda,
    const _Float16* __restrict__ BT,
    void* __restrict__ Cv, int ldc, int M,
    const float* __restrict__ bias, float* __restrict__ bnAcc,
    const float* __restrict__ dvIn, const float* __restrict__ dvOut,
    _Float16* __restrict__ XinS, _Float16* __restrict__ XoutS) {
  __shared__ __align__(16) char lds[128 * KS * 2 + 4096];
  const int t = threadIdx.x;
  const int l = t & 63, w = t >> 6;
  const int col0 = l & 15, rg = l >> 4;
  const int rowbase = blockIdx.x * 256 + w * 64;
  const int sw = (col0 & 7) << 4;

  f32x4 acc[4][8];
  f32x4 zz = {0.f, 0.f, 0.f, 0.f};
#pragma unroll
  for (int a = 0; a < 4; ++a)
#pragma unroll
    for (int n = 0; n < 8; ++n) acc[a][n] = zz;

  for (int ks0 = 0; ks0 < K; ks0 += KS) {
    __syncthreads();
    const int CH = KS / 8;
    for (int u = t; u < 128 * CH; u += 256) {
      int col = u / CH, kc = u % CH;
      f16x8 vch = *(const f16x8*)(BT + (size_t)col * K + ks0 + kc * 8);
      *(f16x8*)(lds + col * (KS * 2) + ((kc * 16) ^ ((col & 7) << 4))) = vch;
    }
    __syncthreads();
#pragma unroll
    for (int ks = 0; ks < KS / 32; ++ks) {
      int kb = ks0 + ks * 32 + rg * 8;
      f16x8 af[4];
#pragma unroll
      for (int a = 0; a < 4; ++a) {
        int rb = rowbase + a * 16;
        if (rb < M) af[a] = loadAfrag(A, (size_t)(rb + col0) * lda + kb);
        else af[a] = (f16x8){0, 0, 0, 0, 0, 0, 0, 0};
      }
      int kc = ks * 4 + rg;
#pragma unroll
      for (int n = 0; n < 8; ++n) {
        f16x8 bf = *(const f16x8*)(lds + (n * 16 + col0) * (KS * 2) + ((kc * 16) ^ sw));
#pragma unroll
        for (int a = 0; a < 4; ++a)
          acc[a][n] = __builtin_amdgcn_mfma_f32_16x16x32_f16(af[a], bf, acc[a][n], 0, 0, 0);
      }
    }
  }

  if (MODE == 1) {
    _Float16* C = (_Float16*)Cv;
#pragma unroll
    for (int a = 0; a < 4; ++a) {
      int rb = rowbase + a * 16;
      if (rb >= M) continue;
#pragma unroll
      for (int r = 0; r < 4; ++r) {
        int row = rb + rg * 4 + r;
        float dIn = dvIn[row], dOut = dvOut[row];
#pragma unroll
        for (int n = 0; n < 8; ++n) {
          int col = n * 16 + col0;
          float val = acc[a][n][r];
          C[(size_t)row * ldc + col] = (_Float16)val;
          XinS[(size_t)row * 128 + col] = (_Float16)(val * dIn);
          XoutS[(size_t)row * 128 + col] = (_Float16)(val * dOut);
        }
      }
    }
  } else {
    float* C = (float*)Cv;
    float sacc[8], qacc[8];
#pragma unroll
    for (int n = 0; n < 8; ++n) { sacc[n] = 0.f; qacc[n] = 0.f; }
#pragma unroll
    for (int a = 0; a < 4; ++a) {
      int rb = rowbase + a * 16;
      if (rb >= M) continue;
#pragma unroll
      for (int n = 0; n < 8; ++n) {
        int col = n * 16 + col0;
        float bi = bias ? bias[col] : 0.f;
#pragma unroll
        for (int r = 0; r < 4; ++r) {
          float val = acc[a][n][r] + bi;
          C[(size_t)(rb + rg * 4 + r) * ldc + col] = val;
          if (BN) { sacc[n] += val; qacc[n] += val * val; }
        }
      }
    }
    if (BN) {
      __syncthreads();
      float* Sb = (float*)lds;
      float* Qb = Sb + 512;
#pragma unroll
      for (int n = 0; n < 8; ++n) {
        float s = sacc[n], q = qacc[n];
        s += __shfl_xor(s, 16); s += __shfl_xor(s, 32);
        q += __shfl_xor(q, 16); q += __shfl_xor(q, 32);
        if (rg == 0) { Sb[w * 128 + n * 16 + col0] = s; Qb[w * 128 + n * 16 + col0] = q; }
      }
      __syncthreads();
      if (t < 128) {
        float s = Sb[t] + Sb[128 + t] + Sb[256 + t] + Sb[384 + t];
        float q = Qb[t] + Qb[128 + t] + Qb[256 + t] + Qb[384 + t];
        atomicAdd(&bnAcc[t], s);
        atomicAdd(&bnAcc[128 + t], q);
      }
    }
  }
}

// ---------------- edge preprocessing ----------------
// Coarse bucket counts for all 4 key arrays, dense per-block partials
// (no global atomics, no write amplification).
__global__ __launch_bounds__(256) void k_ccount(const int* __restrict__ ei,
                                                int* __restrict__ part) {
  __shared__ int lh[4 * NBUK];
  int t = threadIdx.x;
  for (int j = t; j < 4 * NBUK; j += 256) lh[j] = 0;
  __syncthreads();
  int stride = CCB * 256;
  for (int e = blockIdx.x * 256 + t; e < EHALF; e += stride) {
    atomicAdd(&lh[ei[e] >> 9], 1);
    atomicAdd(&lh[NBUK + (ei[EHALF + e] >> 9)], 1);
    atomicAdd(&lh[2 * NBUK + (ei[2 * EHALF + e] >> 9)], 1);
    atomicAdd(&lh[3 * NBUK + (ei[3 * EHALF + e] >> 9)], 1);
  }
  __syncthreads();
  for (int j = t; j < 4 * NBUK; j += 256) part[(size_t)blockIdx.x * (4 * NBUK) + j] = lh[j];
}

// Reduce partials + 4 bucket scans. Sets: 0=srcIn,1=srcOut (4B recs, pad 8),
// 2=dstIn,3=dstOut (8B recs, pad 4; also dense CSR bases).
__global__ __launch_bounds__(1024) void k_bscan4(
    const int* __restrict__ part,
    int* __restrict__ bSI, int* __restrict__ gSI,
    int* __restrict__ bSO, int* __restrict__ gSO,
    int* __restrict__ bDI, int* __restrict__ gDI, int* __restrict__ cBI,
    int* __restrict__ bDO, int* __restrict__ gDO, int* __restrict__ cBO,
    int* __restrict__ offFineIn, int* __restrict__ offFineOut) {
  __shared__ int tot[4 * NBUK];
  __shared__ int sp[256], se[256];
  int t = threadIdx.x;
  for (int j = t; j < 4 * NBUK; j += 1024) {
    int s = 0;
    for (int b = 0; b < CCB; ++b) s += part[(size_t)b * (4 * NBUK) + j];
    tot[j] = s;
  }
  __syncthreads();
  for (int s = 0; s < 4; ++s) {
    int c = 0, pv = 0;
    if (t < 256) {
      c = (t < NBUK) ? tot[s * NBUK + t] : 0;
      pv = (s < 2) ? ((c + 1799) & ~7) : ((c + 771) & ~3);
      sp[t] = pv; se[t] = c;
    }
    __syncthreads();
    for (int o = 1; o < 256; o <<= 1) {
      int ap = 0, ae = 0;
      if (t < 256 && t >= o) { ap = sp[t - o]; ae = se[t - o]; }
      __syncthreads();
      if (t < 256) { sp[t] += ap; se[t] += ae; }
      __syncthreads();
    }
    if (t < NBUK) {
      int exP = sp[t] - pv;
      int exE = se[t] - c;
      if (s == 0)      { bSI[t] = exP; gSI[t] = exP; }
      else if (s == 1) { bSO[t] = exP; gSO[t] = exP; }
      else if (s == 2) { bDI[t] = exP; gDI[t] = exP; cBI[t] = exE; }
      else             { bDO[t] = exP; gDO[t] = exP; cBO[t] = exE; }
    }
    __syncthreads();
  }
  if (t == 0) { offFineIn[N_ENT] = EHALF; offFineOut[N_ENT] = EHALF; }
}

// src-keyed split: 4B records (src&511 | marker), block-exclusive 32B chunks
__global__ __launch_bounds__(256) void k_splitS(
    const int* __restrict__ key, int* __restrict__ gcur, unsigned* __restrict__ rec) {
  __shared__ int bcnt[NBUK], cnt2[NBUK], base[NBUK], nn[NBUK];
  const int t = threadIdx.x;
  const int SPAN = 3907;
  int st = blockIdx.x * SPAN;
  int en = min(st + SPAN, EHALF);
  if (t < NBUK) { bcnt[t] = 0; cnt2[t] = 0; }
  __syncthreads();
  unsigned rr[16]; int bb[16];
#pragma unroll
  for (int j = 0; j < 16; ++j) {
    int e = st + j * 256 + t;
    bb[j] = -1;
    if (e < en) {
      int s = key[e];
      rr[j] = (unsigned)(s & 511) | 0x80000000u;
      int b = s >> 9;
      bb[j] = b;
      atomicAdd(&bcnt[b], 1);
    }
  }
  __syncthreads();
  if (t < NBUK) {
    int n = bcnt[t]; nn[t] = n;
    base[t] = n ? atomicAdd(&gcur[t], (n + 7) & ~7) : 0;
  }
  __syncthreads();
#pragma unroll
  for (int j = 0; j < 16; ++j) {
    if (bb[j] >= 0) {
      int p = atomicAdd(&cnt2[bb[j]], 1);
      rec[(size_t)base[bb[j]] + p] = rr[j];
    }
  }
  __syncthreads();
  if (t < NBUK) {
    int n = nn[t];
    if (n & 7) {
      int pe = (n + 7) & ~7;
      for (int k = n; k < pe; ++k) rec[(size_t)base[t] + k] = 0u;
    }
  }
}

// per-bucket degree histogram -> dinv (dense writes, no global atomics)
__global__ __launch_bounds__(512) void k_dhist(
    const unsigned* __restrict__ recI, const int* __restrict__ bI, const int* __restrict__ gI,
    float* __restrict__ dinvIn,
    const unsigned* __restrict__ recO, const int* __restrict__ bO, const int* __restrict__ gO,
    float* __restrict__ dinvOut) {
  int b = blockIdx.x % NBUK;
  int dir = blockIdx.x / NBUK;
  const unsigned* rec = dir ? recO : recI;
  const int gs = (dir ? bO : bI)[b];
  const int ge = (dir ? gO : gI)[b];
  float* dinv = dir ? dinvOut : dinvIn;
  __shared__ int h[DPB];
  int t = threadIdx.x;
  h[t] = 0;
  __syncthreads();
  for (int i = gs + t; i < ge; i += 512) {
    unsigned r = rec[i];
    if (r >> 31) atomicAdd(&h[r & 511], 1);
  }
  __syncthreads();
  int ent = b * 512 + t;
  if (ent < N_ENT) {
    int d = h[t];
    dinv[ent] = (d > 0) ? rsqrtf((float)d) : 0.f;
  }
}

// dst-keyed split: 8B records, block-exclusive 32B chunks
__global__ __launch_bounds__(256) void k_splitD(
    const int* __restrict__ srcA, const int* __restrict__ dstA, const int* __restrict__ typA,
    int* __restrict__ gcur, uint2* __restrict__ rec) {
  __shared__ int bcnt[NBUK], cnt2[NBUK], base[NBUK], nn[NBUK];
  const int t = threadIdx.x;
  const int SPAN = 3907;
  int st = blockIdx.x * SPAN;
  int en = min(st + SPAN, EHALF);
  if (t < NBUK) { bcnt[t] = 0; cnt2[t] = 0; }
  __syncthreads();
  unsigned w0[16], w1[16]; int bb[16];
#pragma unroll
  for (int j = 0; j < 16; ++j) {
    int e = st + j * 256 + t;
    bb[j] = -1;
    if (e < en) {
      int s = srcA[e], d = dstA[e], ty = typA[e];
      w0[j] = (unsigned)s | ((unsigned)ty << 17);
      w1[j] = (unsigned)(d & 511) | 0x80000000u;
      int b = d >> 9;
      bb[j] = b;
      atomicAdd(&bcnt[b], 1);
    }
  }
  __syncthreads();
  if (t < NBUK) {
    int n = bcnt[t]; nn[t] = n;
    base[t] = n ? atomicAdd(&gcur[t], (n + 3) & ~3) : 0;
  }
  __syncthreads();
#pragma unroll
  for (int j = 0; j < 16; ++j) {
    if (bb[j] >= 0) {
      int p = atomicAdd(&cnt2[bb[j]], 1);
      rec[(size_t)base[bb[j]] + p] = make_uint2(w0[j], w1[j]);
    }
  }
  __syncthreads();
  if (t < NBUK) {
    int n = nn[t];
    if (n & 3) {
      int pe = (n + 3) & ~3;
      for (int k = n; k < pe; ++k) rec[(size_t)base[t] + k] = make_uint2(0u, 0u);
    }
  }
}

// fine sort within bucket -> dense CSR of {xoff, roff} byte-offset records
__global__ __launch_bounds__(512) void k_fsort(
    const uint2* __restrict__ recIn, const int* __restrict__ boffIn, const int* __restrict__ gcurIn,
    const int* __restrict__ csrBIn, uint2* __restrict__ csrIn, int* __restrict__ offFineIn,
    const uint2* __restrict__ recOut, const int* __restrict__ boffOut, const int* __restrict__ gcurOut,
    const int* __restrict__ csrBOut, uint2* __restrict__ csrOut, int* __restrict__ offFineOut) {
  int b = blockIdx.x % NBUK;
  int dir = blockIdx.x / NBUK;
  const uint2* rec = dir ? recOut : recIn;
  const int gs = (dir ? boffOut : boffIn)[b];
  const int ge = (dir ? gcurOut : gcurIn)[b];
  const int cbase = (dir ? csrBOut : csrBIn)[b];
  uint2* csr = dir ? csrOut : csrIn;
  int* offF = dir ? offFineOut : offFineIn;
  __shared__ int h[DPB], sc[DPB], c2[DPB];
  int t = threadIdx.x;
  h[t] = 0; c2[t] = 0;
  __syncthreads();
  for (int i = gs + t; i < ge; i += 512) {
    uint2 r = rec[i];
    if (r.y >> 31) atomicAdd(&h[r.y & 511], 1);
  }
  __syncthreads();
  sc[t] = h[t];
  __syncthreads();
  for (int o = 1; o < 512; o <<= 1) {
    int a = (t >= o) ? sc[t - o] : 0;
    __syncthreads();
    sc[t] += a;
    __syncthreads();
  }
  int excl = sc[t] - h[t];
  int dst = b * 512 + t;
  if (dst < N_ENT) offF[dst] = cbase + excl;
  __syncthreads();
  sc[t] = excl;
  __syncthreads();
  for (int i = gs + t; i < ge; i += 512) {
    uint2 r = rec[i];
    if (r.y >> 31) {
      int d = r.y & 511;
      int p = atomicAdd(&c2[d], 1);
      csr[(size_t)cbase + sc[d] + p] =
          make_uint2((r.x & 0x1FFFFu) << 8, (r.x >> 17) << 9);
    }
  }
}

// ---------------- frequency-domain edge aggregation (one direction) ----------------
__global__ __launch_bounds__(256) void k_agg2(
    const _Float16* __restrict__ XS, const float* __restrict__ Rf,
    const uint2* __restrict__ csr, const int* __restrict__ offF,
    const float* __restrict__ dinvD, _Float16* __restrict__ Aout) {
  int w = threadIdx.x >> 6, l = threadIdx.x & 63;
  int v = blockIdx.x * 4 + w;
  if (v >= N_ENT) return;
  const char* Xb = (const char*)XS;
  const char* Rb = (const char*)Rf;
  const unsigned lx = (unsigned)l * 4u;
  const unsigned lr = (unsigned)l * 8u;
  const bool l0 = (l == 0);
  int b = offF[v], e = offF[v + 1];
  float dv = dinvD[v];
  float ax = 0.f, ay = 0.f;
  int i = b;
  for (; i + 2 <= e; i += 2) {
    uint2 q0 = csr[i], q1 = csr[i + 1];
    f16x2 x0 = *(const f16x2*)(Xb + q0.x + lx);
    float2 r0 = *(const float2*)(Rb + q0.y + lr);
    f16x2 x1 = *(const f16x2*)(Xb + q1.x + lx);
    float2 r1 = *(const float2*)(Rb + q1.y + lr);
    float x0r = (float)x0[0], x0i = (float)x0[1];
    float x1r = (float)x1[0], x1i = (float)x1[1];
    float b0 = l0 ? 0.f : r0.y;
    float d0 = l0 ? r0.y : -r0.x;
    float b1 = l0 ? 0.f : r1.y;
    float d1 = l0 ? r1.y : -r1.x;
    ax = fmaf(x0r, r0.x, ax); ax = fmaf(x0i, b0, ax);
    ay = fmaf(x0r, b0, ay);   ay = fmaf(x0i, d0, ay);
    ax = fmaf(x1r, r1.x, ax); ax = fmaf(x1i, b1, ax);
    ay = fmaf(x1r, b1, ay);   ay = fmaf(x1i, d1, ay);
  }
  if (i < e) {
    uint2 q0 = csr[i];
    f16x2 x0 = *(const f16x2*)(Xb + q0.x + lx);
    float2 r0 = *(const float2*)(Rb + q0.y + lr);
    float x0r = (float)x0[0], x0i = (float)x0[1];
    float b0 = l0 ? 0.f : r0.y;
    float d0 = l0 ? r0.y : -r0.x;
    ax = fmaf(x0r, r0.x, ax); ax = fmaf(x0i, b0, ax);
    ay = fmaf(x0r, b0, ay);   ay = fmaf(x0i, d0, ay);
  }
  *(f16x2*)(Aout + (size_t)v * 384 + 2 * l) = (f16x2){(_Float16)(ax * dv), (_Float16)(ay * dv)};
}

// ---------------- batch norm ----------------
__global__ void k_bnfin(const float* __restrict__ bnAcc, const float* __restrict__ bnw,
                        const float* __restrict__ bnb, float* __restrict__ ss) {
  int c = threadIdx.x;
  float mu = bnAcc[c] * (1.f / (float)N_ENT);
  float var = bnAcc[128 + c] * (1.f / (float)N_ENT) - mu * mu;
  float sc = bnw[c] * rsqrtf(var + 1e-5f);
  ss[c] = sc; ss[128 + c] = bnb[c] - mu * sc;
}

__global__ void k_norm(float* __restrict__ out, const float* __restrict__ ss) {
  int i = blockIdx.x * 256 + threadIdx.x;
  float4* o = (float4*)out;
  float4 v = o[i];
  int c = (i & 31) * 4;
  v.x = v.x * ss[c]     + ss[128 + c];
  v.y = v.y * ss[c + 1] + ss[129 + c];
  v.z = v.z * ss[c + 2] + ss[130 + c];
  v.w = v.w * ss[c + 3] + ss[131 + c];
  o[i] = v;
}

extern "C" void kernel_launch(void* const* d_in, const int* in_sizes, int n_in,
                              void* d_out, int out_size, void* d_ws, size_t ws_size,
                              hipStream_t stream) {
  const float* x       = (const float*)d_in[0];
  const float* rel     = (const float*)d_in[1];
  const float* w_in    = (const float*)d_in[2];
  const float* w_out   = (const float*)d_in[3];
  const float* w_loop  = (const float*)d_in[4];
  const float* w_rel   = (const float*)d_in[5];
  const float* looprel = (const float*)d_in[6];
  const float* bias    = (const float*)d_in[7];
  const float* bnw     = (const float*)d_in[8];
  const float* bnb     = (const float*)d_in[9];
  const int*   ei      = (const int*)d_in[10];
  const int*   et      = (const int*)d_in[11];
  float* out = (float*)d_out;

  char* p = (char*)d_ws;
  auto alloc = [&](size_t bytes) -> void* {
    void* r = (void*)p;
    p += (bytes + 255) & ~(size_t)255;
    return r;
  };
  const size_t RECCAP8 = EHALF + NBUK * 776;    // dst splits (8B recs)
  const size_t RECCAP4 = EHALF + NBUK * 1808;   // src splits (4B recs)
  _Float16* Abuf  = (_Float16*)alloc((size_t)N_ENT * 384 * 2);
  _Float16* XinS  = (_Float16*)alloc((size_t)N_ENT * 128 * 2);
  _Float16* XoutS = (_Float16*)alloc((size_t)N_ENT * 128 * 2);
  _Float16* WT    = (_Float16*)alloc(128 * 384 * 2);
  _Float16* FtabT = (_Float16*)alloc(128 * 128 * 2);
  float* Wstack   = (float*)alloc(384 * 128 * 4);
  float* Ftab     = (float*)alloc(128 * 128 * 4);
  float* Gtab     = (float*)alloc(128 * 128 * 4);
  float* Rf       = (float*)alloc(501 * 128 * 4);
  float* dinvIn   = (float*)alloc(N_ENT * 4);
  float* dinvOut  = (float*)alloc(N_ENT * 4);
  int*   part     = (int*)alloc((size_t)CCB * 4 * NBUK * 4);
  int*   bSI      = (int*)alloc(NBUK * 4);
  int*   gSI      = (int*)alloc(NBUK * 4);
  int*   bSO      = (int*)alloc(NBUK * 4);
  int*   gSO      = (int*)alloc(NBUK * 4);
  int*   bDI      = (int*)alloc(NBUK * 4);
  int*   gDI      = (int*)alloc(NBUK * 4);
  int*   cBI      = (int*)alloc((NBUK + 1) * 4);
  int*   bDO      = (int*)alloc(NBUK * 4);
  int*   gDO      = (int*)alloc(NBUK * 4);
  int*   cBO      = (int*)alloc((NBUK + 1) * 4);
  int*   offFineIn  = (int*)alloc((N_ENT + 1) * 4);
  int*   offFineOut = (int*)alloc((N_ENT + 1) * 4);
  unsigned* recSI = (unsigned*)alloc(RECCAP4 * 4);
  unsigned* recSO = (unsigned*)alloc(RECCAP4 * 4);
  uint2* recDI    = (uint2*)alloc(RECCAP8 * 8);
  uint2* recDO    = (uint2*)alloc(RECCAP8 * 8);
  uint2* csrIn    = (uint2*)alloc((size_t)EHALF * 8);
  uint2* csrOut   = (uint2*)alloc((size_t)EHALF * 8);
  float* bnAcc    = (float*)alloc(256 * 4);
  float* ss       = (float*)alloc(256 * 4);

  hipMemsetAsync(bnAcc, 0, 256 * 4, stream);

  // tables + relation spectra + folded weight stack
  k_tabs<<<64, 256, 0, stream>>>(Ftab, Gtab, FtabT);
  k_dftrel<<<501, 128, 0, stream>>>(rel, looprel, Ftab, Rf);
  gemm128<<<2, 256, 0, stream>>>(Gtab, 128, w_in,   Wstack,             128, 128, 128);
  gemm128<<<2, 256, 0, stream>>>(Gtab, 128, w_out,  Wstack + 128 * 128, 128, 128, 128);
  gemm128<<<2, 256, 0, stream>>>(Gtab, 128, w_loop, Wstack + 256 * 128, 128, 128, 128);
  k_rotloop<<<64, 128, 0, stream>>>(Wstack + 256 * 128, Rf + 500 * 128);
  k_wt<<<192, 256, 0, stream>>>(Wstack, WT, 384);

  // coarse counts (dense partials) + all 4 bucket scans
  k_ccount<<<CCB, 256, 0, stream>>>(ei, part);
  k_bscan4<<<1, 1024, 0, stream>>>(part, bSI, gSI, bSO, gSO,
                                   bDI, gDI, cBI, bDO, gDO, cBO,
                                   offFineIn, offFineOut);

  // splits (write-amp-free): src-keyed (degrees) + dst-keyed (CSR)
  k_splitS<<<256, 256, 0, stream>>>(ei,         gSI, recSI);
  k_splitS<<<256, 256, 0, stream>>>(ei + EHALF, gSO, recSO);
  k_splitD<<<256, 256, 0, stream>>>(ei,         ei + 2 * EHALF, et,         gDI, recDI);
  k_splitD<<<256, 256, 0, stream>>>(ei + EHALF, ei + 3 * EHALF, et + EHALF, gDO, recDO);

  // degrees -> dinv (per-bucket LDS hist, dense writes)
  k_dhist<<<2 * NBUK, 512, 0, stream>>>(recSI, bSI, gSI, dinvIn, recSO, bSO, gSO, dinvOut);

  // Xf = rfft(x) via f16 MFMA; epilogue writes dinv-prescaled copies
  mgemm<128, 128, 1, false, float><<<(N_ENT + 255) / 256, 256, 0, stream>>>(
      x, 128, FtabT, (void*)(Abuf + 256), 384, N_ENT, nullptr, nullptr,
      dinvIn, dinvOut, XinS, XoutS);

  // fine CSR sort per bucket
  k_fsort<<<2 * NBUK, 512, 0, stream>>>(recDI, bDI, gDI, cBI, csrIn, offFineIn,
                                        recDO, bDO, gDO, cBO, csrOut, offFineOut);

  // frequency-domain aggregation, one pass per direction
  k_agg2<<<N_ENT / 4, 256, 0, stream>>>(XinS, Rf, csrIn, offFineIn, dinvIn, Abuf);
  k_agg2<<<N_ENT / 4, 256, 0, stream>>>(XoutS, Rf, csrOut, offFineOut, dinvOut, Abuf + 128);

  // fused output GEMM (f16 MFMA): [c_in|c_out|Xf] @ Wstack + bias, BN stats
  mgemm<384, 192, 0, true, _Float16><<<(N_ENT + 255) / 256, 256, 0, stream>>>(
      Abuf, 384, WT, (void*)out, 128, N_ENT, bias, bnAcc,
      nullptr, nullptr, nullptr, nullptr);
  k_bnfin<<<1, 128, 0, stream>>>(bnAcc, bnw, bnb, ss);
  k_norm<<<(N_ENT * 128 / 4) / 256, 256, 0, stream>>>(out, ss);

  // rel_out = rel_embed @ w_rel (fp32)
  gemm128<<<(N_REL + 63) / 64, 256, 0, stream>>>(rel, 128, w_rel, out + (size_t)N_ENT * 128, 128, N_REL, 128);
}

// Round 6
// 417.717 us; speedup vs baseline: 1.1286x; 1.0715x over previous
//
#include <hip/hip_runtime.h>
#include <cmath>

#define N_ENT 100000
#define EHALF 1000000
#define N_REL 500
#define NBUK 196          // ceil(100000/512) coarse buckets (key>>9)
#define DPB 512           // entities per bucket
#define CCB 512           // k_ccount blocks

#ifndef M_PI
#define M_PI 3.14159265358979323846
#endif

typedef _Float16 f16x8 __attribute__((ext_vector_type(8)));
typedef _Float16 f16x4 __attribute__((ext_vector_type(4)));
typedef _Float16 f16x2 __attribute__((ext_vector_type(2)));
typedef float f32x4 __attribute__((ext_vector_type(4)));

// ---------------- DFT tables ----------------
// Spectrum layout per row (128): slot0=Re(bin0), slot1=Re(bin64),
// slot 2f=Re(bin f), slot 2f+1=Im(bin f), f=1..63.
__global__ void k_tabs(float* __restrict__ Ftab, float* __restrict__ Gtab,
                       _Float16* __restrict__ FtabT) {
  int i = blockIdx.x * 256 + threadIdx.x;
  if (i >= 128 * 128) return;
  int n = i >> 7, s = i & 127;
  float fv, gv;
  if (s == 0) { fv = 1.f; gv = 1.f / 384.f; }
  else if (s == 1) { float sg = (n & 1) ? -1.f : 1.f; fv = sg; gv = sg / 384.f; }
  else {
    int f = s >> 1;
    double ang = 2.0 * M_PI * (double)((f * n) & 127) / 128.0;
    if (!(s & 1)) { double c = cos(ang); fv = (float)c; gv = (float)(c * (2.0 / 384.0)); }
    else { double sv = sin(ang); fv = (float)(-sv); gv = (float)(-sv * (2.0 / 384.0)); }
  }
  Ftab[n * 128 + s] = fv;
  Gtab[s * 128 + n] = gv;
  FtabT[s * 128 + n] = (_Float16)fv;
}

__global__ void k_dftrel(const float* __restrict__ rel, const float* __restrict__ looprel,
                         const float* __restrict__ Ftab, float* __restrict__ Rf) {
  int r = blockIdx.x, s = threadIdx.x;
  const float* row = (r < N_REL) ? rel + (size_t)r * 128 : looprel;
  float acc = 0.f;
  for (int n = 0; n < 128; ++n) acc += row[n] * Ftab[n * 128 + s];
  Rf[(size_t)r * 128 + s] = acc;
}

// per-lane pre-swizzled R table: RfL[r][lane] = (A,B,C,D) f16
// lane 0 (real bins 0,64): (r0, 0, 0, r64); lane l>=1: (rx, ry, ry, -rx)
__global__ void k_rpack(const float* __restrict__ Rf, _Float16* __restrict__ RfL) {
  int r = blockIdx.x, l = threadIdx.x;  // 64 threads
  const float* row = Rf + (size_t)r * 128;
  f16x4 o;
  if (l == 0) {
    o = (f16x4){(_Float16)row[0], (_Float16)0.f, (_Float16)0.f, (_Float16)row[1]};
  } else {
    float rx = row[2 * l], ry = row[2 * l + 1];
    o = (f16x4){(_Float16)rx, (_Float16)ry, (_Float16)ry, (_Float16)(-rx)};
  }
  ((f16x4*)RfL)[(size_t)r * 64 + l] = o;
}

__global__ void k_rotloop(float* __restrict__ Wl, const float* __restrict__ Rfl) {
  int c = threadIdx.x;
  int f = blockIdx.x;
  if (f == 0) {
    Wl[c]       = Rfl[0] * Wl[c];
    Wl[128 + c] = Rfl[1] * Wl[128 + c];
  } else {
    float rr = Rfl[2 * f], ri = Rfl[2 * f + 1];
    float a = Wl[2 * f * 128 + c], b = Wl[(2 * f + 1) * 128 + c];
    Wl[2 * f * 128 + c]       = rr * a + ri * b;
    Wl[(2 * f + 1) * 128 + c] = ri * a - rr * b;
  }
}

__global__ void k_wt(const float* __restrict__ W, _Float16* __restrict__ WT, int K) {
  int i = blockIdx.x * 256 + threadIdx.x;
  if (i >= K * 128) return;
  int k = i >> 7, c = i & 127;
  WT[(size_t)c * K + k] = (_Float16)W[i];
}

// ---------------- fp32 GEMM (small preps + rel_out), N fixed = 128 ----------------
__global__ __launch_bounds__(256) void gemm128(
    const float* __restrict__ A, int lda,
    const float* __restrict__ B,
    float* __restrict__ C, int ldc,
    int M, int K) {
  __shared__ float As[64][64];
  __shared__ float Bs[64][128];
  const int t = threadIdx.x;
  const int m0 = blockIdx.x * 64;
  const int cg = t & 31;
  const int eg = t >> 5;
  float acc[8][4];
#pragma unroll
  for (int i = 0; i < 8; ++i)
#pragma unroll
    for (int j = 0; j < 4; ++j) acc[i][j] = 0.f;

  for (int k0 = 0; k0 < K; k0 += 64) {
#pragma unroll
    for (int p = 0; p < 4; ++p) {
      int idx = t + p * 256;
      int r = idx >> 4, c4 = idx & 15;
      int gr = m0 + r;
      float4 v = make_float4(0.f, 0.f, 0.f, 0.f);
      if (gr < M) v = *(const float4*)(A + (size_t)gr * lda + k0 + c4 * 4);
      *(float4*)&As[r][c4 * 4] = v;
    }
#pragma unroll
    for (int p = 0; p < 8; ++p) {
      int idx = t + p * 256;
      int r = idx >> 5, c4 = idx & 31;
      float4 v = *(const float4*)(B + (size_t)(k0 + r) * 128 + c4 * 4);
      *(float4*)&Bs[r][c4 * 4] = v;
    }
    __syncthreads();
#pragma unroll
    for (int k = 0; k < 64; ++k) {
      float4 bv = *(float4*)&Bs[k][cg * 4];
#pragma unroll
      for (int i = 0; i < 8; ++i) {
        float av = As[eg * 8 + i][k];
        acc[i][0] += av * bv.x; acc[i][1] += av * bv.y;
        acc[i][2] += av * bv.z; acc[i][3] += av * bv.w;
      }
    }
    __syncthreads();
  }
#pragma unroll
  for (int i = 0; i < 8; ++i) {
    int gr = m0 + eg * 8 + i;
    if (gr < M) {
      float4 v = make_float4(acc[i][0], acc[i][1], acc[i][2], acc[i][3]);
      *(float4*)(C + (size_t)gr * ldc + cg * 4) = v;
    }
  }
}

// ---------------- f16 MFMA GEMM, N=128 ----------------
__device__ inline f16x8 loadAfrag(const _Float16* A, size_t off) {
  return *(const f16x8*)(A + off);
}
__device__ inline f16x8 loadAfrag(const float* A, size_t off) {
  float4 u = *(const float4*)(A + off);
  float4 v = *(const float4*)(A + off + 4);
  return (f16x8){(_Float16)u.x, (_Float16)u.y, (_Float16)u.z, (_Float16)u.w,
                 (_Float16)v.x, (_Float16)v.y, (_Float16)v.z, (_Float16)v.w};
}

// MODE 0: fp32 C (+bias, +BN stats). MODE 1: f16 C (ldc) + dinv-prescaled copies.
template<int K, int KS, int MODE, bool BN, typename AT>
__global__ __launch_bounds__(256) void mgemm(
    const AT* __restrict__ A, int lda,
    const _Float16* __restrict__ BT,
    void* __restrict__ Cv, int ldc, int M,
    const float* __restrict__ bias, float* __restrict__ bnAcc,
    const float* __restrict__ dvIn, const float* __restrict__ dvOut,
    _Float16* __restrict__ XinS, _Float16* __restrict__ XoutS) {
  __shared__ __align__(16) char lds[128 * KS * 2 + 4096];
  const int t = threadIdx.x;
  const int l = t & 63, w = t >> 6;
  const int col0 = l & 15, rg = l >> 4;
  const int rowbase = blockIdx.x * 256 + w * 64;
  const int sw = (col0 & 7) << 4;

  f32x4 acc[4][8];
  f32x4 zz = {0.f, 0.f, 0.f, 0.f};
#pragma unroll
  for (int a = 0; a < 4; ++a)
#pragma unroll
    for (int n = 0; n < 8; ++n) acc[a][n] = zz;

  for (int ks0 = 0; ks0 < K; ks0 += KS) {
    __syncthreads();
    const int CH = KS / 8;
    for (int u = t; u < 128 * CH; u += 256) {
      int col = u / CH, kc = u % CH;
      f16x8 vch = *(const f16x8*)(BT + (size_t)col * K + ks0 + kc * 8);
      *(f16x8*)(lds + col * (KS * 2) + ((kc * 16) ^ ((col & 7) << 4))) = vch;
    }
    __syncthreads();
#pragma unroll
    for (int ks = 0; ks < KS / 32; ++ks) {
      int kb = ks0 + ks * 32 + rg * 8;
      f16x8 af[4];
#pragma unroll
      for (int a = 0; a < 4; ++a) {
        int rb = rowbase + a * 16;
        if (rb < M) af[a] = loadAfrag(A, (size_t)(rb + col0) * lda + kb);
        else af[a] = (f16x8){0, 0, 0, 0, 0, 0, 0, 0};
      }
      int kc = ks * 4 + rg;
#pragma unroll
      for (int n = 0; n < 8; ++n) {
        f16x8 bf = *(const f16x8*)(lds + (n * 16 + col0) * (KS * 2) + ((kc * 16) ^ sw));
#pragma unroll
        for (int a = 0; a < 4; ++a)
          acc[a][n] = __builtin_amdgcn_mfma_f32_16x16x32_f16(af[a], bf, acc[a][n], 0, 0, 0);
      }
    }
  }

  if (MODE == 1) {
    _Float16* C = (_Float16*)Cv;
#pragma unroll
    for (int a = 0; a < 4; ++a) {
      int rb = rowbase + a * 16;
      if (rb >= M) continue;
#pragma unroll
      for (int r = 0; r < 4; ++r) {
        int row = rb + rg * 4 + r;
        float dIn = dvIn[row], dOut = dvOut[row];
#pragma unroll
        for (int n = 0; n < 8; ++n) {
          int col = n * 16 + col0;
          float val = acc[a][n][r];
          C[(size_t)row * ldc + col] = (_Float16)val;
          XinS[(size_t)row * 128 + col] = (_Float16)(val * dIn);
          XoutS[(size_t)row * 128 + col] = (_Float16)(val * dOut);
        }
      }
    }
  } else {
    float* C = (float*)Cv;
    float sacc[8], qacc[8];
#pragma unroll
    for (int n = 0; n < 8; ++n) { sacc[n] = 0.f; qacc[n] = 0.f; }
#pragma unroll
    for (int a = 0; a < 4; ++a) {
      int rb = rowbase + a * 16;
      if (rb >= M) continue;
#pragma unroll
      for (int n = 0; n < 8; ++n) {
        int col = n * 16 + col0;
        float bi = bias ? bias[col] : 0.f;
#pragma unroll
        for (int r = 0; r < 4; ++r) {
          float val = acc[a][n][r] + bi;
          C[(size_t)(rb + rg * 4 + r) * ldc + col] = val;
          if (BN) { sacc[n] += val; qacc[n] += val * val; }
        }
      }
    }
    if (BN) {
      __syncthreads();
      float* Sb = (float*)lds;
      float* Qb = Sb + 512;
#pragma unroll
      for (int n = 0; n < 8; ++n) {
        float s = sacc[n], q = qacc[n];
        s += __shfl_xor(s, 16); s += __shfl_xor(s, 32);
        q += __shfl_xor(q, 16); q += __shfl_xor(q, 32);
        if (rg == 0) { Sb[w * 128 + n * 16 + col0] = s; Qb[w * 128 + n * 16 + col0] = q; }
      }
      __syncthreads();
      if (t < 128) {
        float s = Sb[t] + Sb[128 + t] + Sb[256 + t] + Sb[384 + t];
        float q = Qb[t] + Qb[128 + t] + Qb[256 + t] + Qb[384 + t];
        atomicAdd(&bnAcc[t], s);
        atomicAdd(&bnAcc[128 + t], q);
      }
    }
  }
}

// ---------------- edge preprocessing ----------------
// Coarse bucket counts for all 4 key arrays: LDS-privatized, then one
// global atomicAdd per (block, bucket) into 784 resident counters.
__global__ __launch_bounds__(256) void k_ccount(const int* __restrict__ ei,
                                                int* __restrict__ btot) {
  __shared__ int lh[4 * NBUK];
  int t = threadIdx.x;
  for (int j = t; j < 4 * NBUK; j += 256) lh[j] = 0;
  __syncthreads();
  int stride = CCB * 256;
  for (int e = blockIdx.x * 256 + t; e < EHALF; e += stride) {
    atomicAdd(&lh[ei[e] >> 9], 1);
    atomicAdd(&lh[NBUK + (ei[EHALF + e] >> 9)], 1);
    atomicAdd(&lh[2 * NBUK + (ei[2 * EHALF + e] >> 9)], 1);
    atomicAdd(&lh[3 * NBUK + (ei[3 * EHALF + e] >> 9)], 1);
  }
  __syncthreads();
  for (int j = t; j < 4 * NBUK; j += 256) {
    int c = lh[j];
    if (c) atomicAdd(&btot[j], c);
  }
}

// 4 bucket scans. Sets: 0=srcIn,1=srcOut (4B recs, pad 8),
// 2=dstIn,3=dstOut (8B recs, pad 4; also dense CSR bases).
__global__ __launch_bounds__(256) void k_bscan4(
    const int* __restrict__ btot,
    int* __restrict__ bSI, int* __restrict__ gSI,
    int* __restrict__ bSO, int* __restrict__ gSO,
    int* __restrict__ bDI, int* __restrict__ gDI, int* __restrict__ cBI,
    int* __restrict__ bDO, int* __restrict__ gDO, int* __restrict__ cBO,
    int* __restrict__ offFineIn, int* __restrict__ offFineOut) {
  __shared__ int sp[256], se[256];
  int t = threadIdx.x;
  for (int s = 0; s < 4; ++s) {
    int c = (t < NBUK) ? btot[s * NBUK + t] : 0;
    int pv = (s < 2) ? ((c + 1799) & ~7) : ((c + 771) & ~3);
    sp[t] = pv; se[t] = c;
    __syncthreads();
    for (int o = 1; o < 256; o <<= 1) {
      int ap = (t >= o) ? sp[t - o] : 0;
      int ae = (t >= o) ? se[t - o] : 0;
      __syncthreads();
      sp[t] += ap; se[t] += ae;
      __syncthreads();
    }
    if (t < NBUK) {
      int exP = sp[t] - pv;
      int exE = se[t] - c;
      if (s == 0)      { bSI[t] = exP; gSI[t] = exP; }
      else if (s == 1) { bSO[t] = exP; gSO[t] = exP; }
      else if (s == 2) { bDI[t] = exP; gDI[t] = exP; cBI[t] = exE; }
      else             { bDO[t] = exP; gDO[t] = exP; cBO[t] = exE; }
    }
    __syncthreads();
  }
  if (t == 0) { offFineIn[N_ENT] = EHALF; offFineOut[N_ENT] = EHALF; }
}

// src-keyed split: 4B records (src&511 | marker), block-exclusive 32B chunks
__global__ __launch_bounds__(256) void k_splitS(
    const int* __restrict__ key, int* __restrict__ gcur, unsigned* __restrict__ rec) {
  __shared__ int bcnt[NBUK], cnt2[NBUK], base[NBUK], nn[NBUK];
  const int t = threadIdx.x;
  const int SPAN = 3907;
  int st = blockIdx.x * SPAN;
  int en = min(st + SPAN, EHALF);
  if (t < NBUK) { bcnt[t] = 0; cnt2[t] = 0; }
  __syncthreads();
  unsigned rr[16]; int bb[16];
#pragma unroll
  for (int j = 0; j < 16; ++j) {
    int e = st + j * 256 + t;
    bb[j] = -1;
    if (e < en) {
      int s = key[e];
      rr[j] = (unsigned)(s & 511) | 0x80000000u;
      int b = s >> 9;
      bb[j] = b;
      atomicAdd(&bcnt[b], 1);
    }
  }
  __syncthreads();
  if (t < NBUK) {
    int n = bcnt[t]; nn[t] = n;
    base[t] = n ? atomicAdd(&gcur[t], (n + 7) & ~7) : 0;
  }
  __syncthreads();
#pragma unroll
  for (int j = 0; j < 16; ++j) {
    if (bb[j] >= 0) {
      int p = atomicAdd(&cnt2[bb[j]], 1);
      rec[(size_t)base[bb[j]] + p] = rr[j];
    }
  }
  __syncthreads();
  if (t < NBUK) {
    int n = nn[t];
    if (n & 7) {
      int pe = (n + 7) & ~7;
      for (int k = n; k < pe; ++k) rec[(size_t)base[t] + k] = 0u;
    }
  }
}

// per-bucket degree histogram -> dinv (dense writes, no global atomics)
__global__ __launch_bounds__(512) void k_dhist(
    const unsigned* __restrict__ recI, const int* __restrict__ bI, const int* __restrict__ gI,
    float* __restrict__ dinvIn,
    const unsigned* __restrict__ recO, const int* __restrict__ bO, const int* __restrict__ gO,
    float* __restrict__ dinvOut) {
  int b = blockIdx.x % NBUK;
  int dir = blockIdx.x / NBUK;
  const unsigned* rec = dir ? recO : recI;
  const int gs = (dir ? bO : bI)[b];
  const int ge = (dir ? gO : gI)[b];
  float* dinv = dir ? dinvOut : dinvIn;
  __shared__ int h[DPB];
  int t = threadIdx.x;
  h[t] = 0;
  __syncthreads();
  for (int i = gs + t; i < ge; i += 512) {
    unsigned r = rec[i];
    if (r >> 31) atomicAdd(&h[r & 511], 1);
  }
  __syncthreads();
  int ent = b * 512 + t;
  if (ent < N_ENT) {
    int d = h[t];
    dinv[ent] = (d > 0) ? rsqrtf((float)d) : 0.f;
  }
}

// dst-keyed split: 8B records, block-exclusive 32B chunks
__global__ __launch_bounds__(256) void k_splitD(
    const int* __restrict__ srcA, const int* __restrict__ dstA, const int* __restrict__ typA,
    int* __restrict__ gcur, uint2* __restrict__ rec) {
  __shared__ int bcnt[NBUK], cnt2[NBUK], base[NBUK], nn[NBUK];
  const int t = threadIdx.x;
  const int SPAN = 3907;
  int st = blockIdx.x * SPAN;
  int en = min(st + SPAN, EHALF);
  if (t < NBUK) { bcnt[t] = 0; cnt2[t] = 0; }
  __syncthreads();
  unsigned w0[16], w1[16]; int bb[16];
#pragma unroll
  for (int j = 0; j < 16; ++j) {
    int e = st + j * 256 + t;
    bb[j] = -1;
    if (e < en) {
      int s = srcA[e], d = dstA[e], ty = typA[e];
      w0[j] = (unsigned)s | ((unsigned)ty << 17);
      w1[j] = (unsigned)(d & 511) | 0x80000000u;
      int b = d >> 9;
      bb[j] = b;
      atomicAdd(&bcnt[b], 1);
    }
  }
  __syncthreads();
  if (t < NBUK) {
    int n = bcnt[t]; nn[t] = n;
    base[t] = n ? atomicAdd(&gcur[t], (n + 3) & ~3) : 0;
  }
  __syncthreads();
#pragma unroll
  for (int j = 0; j < 16; ++j) {
    if (bb[j] >= 0) {
      int p = atomicAdd(&cnt2[bb[j]], 1);
      rec[(size_t)base[bb[j]] + p] = make_uint2(w0[j], w1[j]);
    }
  }
  __syncthreads();
  if (t < NBUK) {
    int n = nn[t];
    if (n & 3) {
      int pe = (n + 3) & ~3;
      for (int k = n; k < pe; ++k) rec[(size_t)base[t] + k] = make_uint2(0u, 0u);
    }
  }
}

// fine sort within bucket -> dense CSR of {xoff, roff} byte-offset records
__global__ __launch_bounds__(512) void k_fsort(
    const uint2* __restrict__ recIn, const int* __restrict__ boffIn, const int* __restrict__ gcurIn,
    const int* __restrict__ csrBIn, uint2* __restrict__ csrIn, int* __restrict__ offFineIn,
    const uint2* __restrict__ recOut, const int* __restrict__ boffOut, const int* __restrict__ gcurOut,
    const int* __restrict__ csrBOut, uint2* __restrict__ csrOut, int* __restrict__ offFineOut) {
  int b = blockIdx.x % NBUK;
  int dir = blockIdx.x / NBUK;
  const uint2* rec = dir ? recOut : recIn;
  const int gs = (dir ? boffOut : boffIn)[b];
  const int ge = (dir ? gcurOut : gcurIn)[b];
  const int cbase = (dir ? csrBOut : csrBIn)[b];
  uint2* csr = dir ? csrOut : csrIn;
  int* offF = dir ? offFineOut : offFineIn;
  __shared__ int h[DPB], sc[DPB], c2[DPB];
  int t = threadIdx.x;
  h[t] = 0; c2[t] = 0;
  __syncthreads();
  for (int i = gs + t; i < ge; i += 512) {
    uint2 r = rec[i];
    if (r.y >> 31) atomicAdd(&h[r.y & 511], 1);
  }
  __syncthreads();
  sc[t] = h[t];
  __syncthreads();
  for (int o = 1; o < 512; o <<= 1) {
    int a = (t >= o) ? sc[t - o] : 0;
    __syncthreads();
    sc[t] += a;
    __syncthreads();
  }
  int excl = sc[t] - h[t];
  int dst = b * 512 + t;
  if (dst < N_ENT) offF[dst] = cbase + excl;
  __syncthreads();
  sc[t] = excl;
  __syncthreads();
  for (int i = gs + t; i < ge; i += 512) {
    uint2 r = rec[i];
    if (r.y >> 31) {
      int d = r.y & 511;
      int p = atomicAdd(&c2[d], 1);
      csr[(size_t)cbase + sc[d] + p] =
          make_uint2((r.x & 0x1FFFFu) << 8, (r.x >> 17) << 9);
    }
  }
}

// ---------------- frequency-domain edge aggregation (both directions) ----------------
// XS tables: dinv-prescaled spectra f16 [N_ENT][128]. RfL: per-lane f16x4.
// Wave per entity; In and Out edge streams interleaved for ILP (4 gathers
// in flight). Per edge: 1×4B X load + 1×8B R load + 4 v_fma_mix.
__global__ __launch_bounds__(256) void k_agg(
    const _Float16* __restrict__ XinS, const _Float16* __restrict__ XoutS,
    const _Float16* __restrict__ RfL,
    const uint2* __restrict__ csrIn, const int* __restrict__ offIn,
    const uint2* __restrict__ csrOut, const int* __restrict__ offOut,
    const float* __restrict__ dinvIn, const float* __restrict__ dinvOut,
    _Float16* __restrict__ Aout) {
  const int w = threadIdx.x >> 6, l = threadIdx.x & 63;
  const int v = blockIdx.x * 4 + w;
  const char* XbI = (const char*)XinS;
  const char* XbO = (const char*)XoutS;
  const char* Rb  = (const char*)RfL;
  const unsigned lx = (unsigned)l * 4u;
  const unsigned lr = (unsigned)l * 8u;
  int i = offIn[v], ie = offIn[v + 1];
  int o = offOut[v], oe = offOut[v + 1];
  float aix = 0.f, aiy = 0.f, aox = 0.f, aoy = 0.f;

  while (i + 2 <= ie && o + 2 <= oe) {
    uint2 a0 = csrIn[i], a1 = csrIn[i + 1];
    uint2 b0 = csrOut[o], b1 = csrOut[o + 1];
    f16x2 xa0 = *(const f16x2*)(XbI + a0.x + lx);
    f16x4 ra0 = *(const f16x4*)(Rb + a0.y + lr);
    f16x2 xa1 = *(const f16x2*)(XbI + a1.x + lx);
    f16x4 ra1 = *(const f16x4*)(Rb + a1.y + lr);
    f16x2 xb0 = *(const f16x2*)(XbO + b0.x + lx);
    f16x4 rb0 = *(const f16x4*)(Rb + b0.y + lr);
    f16x2 xb1 = *(const f16x2*)(XbO + b1.x + lx);
    f16x4 rb1 = *(const f16x4*)(Rb + b1.y + lr);
    aix = fmaf((float)xa0[0], (float)ra0[0], aix); aix = fmaf((float)xa0[1], (float)ra0[1], aix);
    aiy = fmaf((float)xa0[0], (float)ra0[2], aiy); aiy = fmaf((float)xa0[1], (float)ra0[3], aiy);
    aix = fmaf((float)xa1[0], (float)ra1[0], aix); aix = fmaf((float)xa1[1], (float)ra1[1], aix);
    aiy = fmaf((float)xa1[0], (float)ra1[2], aiy); aiy = fmaf((float)xa1[1], (float)ra1[3], aiy);
    aox = fmaf((float)xb0[0], (float)rb0[0], aox); aox = fmaf((float)xb0[1], (float)rb0[1], aox);
    aoy = fmaf((float)xb0[0], (float)rb0[2], aoy); aoy = fmaf((float)xb0[1], (float)rb0[3], aoy);
    aox = fmaf((float)xb1[0], (float)rb1[0], aox); aox = fmaf((float)xb1[1], (float)rb1[1], aox);
    aoy = fmaf((float)xb1[0], (float)rb1[2], aoy); aoy = fmaf((float)xb1[1], (float)rb1[3], aoy);
    i += 2; o += 2;
  }
  while (i + 2 <= ie) {
    uint2 a0 = csrIn[i], a1 = csrIn[i + 1];
    f16x2 xa0 = *(const f16x2*)(XbI + a0.x + lx);
    f16x4 ra0 = *(const f16x4*)(Rb + a0.y + lr);
    f16x2 xa1 = *(const f16x2*)(XbI + a1.x + lx);
    f16x4 ra1 = *(const f16x4*)(Rb + a1.y + lr);
    aix = fmaf((float)xa0[0], (float)ra0[0], aix); aix = fmaf((float)xa0[1], (float)ra0[1], aix);
    aiy = fmaf((float)xa0[0], (float)ra0[2], aiy); aiy = fmaf((float)xa0[1], (float)ra0[3], aiy);
    aix = fmaf((float)xa1[0], (float)ra1[0], aix); aix = fmaf((float)xa1[1], (float)ra1[1], aix);
    aiy = fmaf((float)xa1[0], (float)ra1[2], aiy); aiy = fmaf((float)xa1[1], (float)ra1[3], aiy);
    i += 2;
  }
  while (o + 2 <= oe) {
    uint2 b0 = csrOut[o], b1 = csrOut[o + 1];
    f16x2 xb0 = *(const f16x2*)(XbO + b0.x + lx);
    f16x4 rb0 = *(const f16x4*)(Rb + b0.y + lr);
    f16x2 xb1 = *(const f16x2*)(XbO + b1.x + lx);
    f16x4 rb1 = *(const f16x4*)(Rb + b1.y + lr);
    aox = fmaf((float)xb0[0], (float)rb0[0], aox); aox = fmaf((float)xb0[1], (float)rb0[1], aox);
    aoy = fmaf((float)xb0[0], (float)rb0[2], aoy); aoy = fmaf((float)xb0[1], (float)rb0[3], aoy);
    aox = fmaf((float)xb1[0], (float)rb1[0], aox); aox = fmaf((float)xb1[1], (float)rb1[1], aox);
    aoy = fmaf((float)xb1[0], (float)rb1[2], aoy); aoy = fmaf((float)xb1[1], (float)rb1[3], aoy);
    o += 2;
  }
  if (i < ie) {
    uint2 a0 = csrIn[i];
    f16x2 xa0 = *(const f16x2*)(XbI + a0.x + lx);
    f16x4 ra0 = *(const f16x4*)(Rb + a0.y + lr);
    aix = fmaf((float)xa0[0], (float)ra0[0], aix); aix = fmaf((float)xa0[1], (float)ra0[1], aix);
    aiy = fmaf((float)xa0[0], (float)ra0[2], aiy); aiy = fmaf((float)xa0[1], (float)ra0[3], aiy);
  }
  if (o < oe) {
    uint2 b0 = csrOut[o];
    f16x2 xb0 = *(const f16x2*)(XbO + b0.x + lx);
    f16x4 rb0 = *(const f16x4*)(Rb + b0.y + lr);
    aox = fmaf((float)xb0[0], (float)rb0[0], aox); aox = fmaf((float)xb0[1], (float)rb0[1], aox);
    aoy = fmaf((float)xb0[0], (float)rb0[2], aoy); aoy = fmaf((float)xb0[1], (float)rb0[3], aoy);
  }
  float dvI = dinvIn[v], dvO = dinvOut[v];
  *(f16x2*)(Aout + (size_t)v * 384 + 2 * l) =
      (f16x2){(_Float16)(aix * dvI), (_Float16)(aiy * dvI)};
  *(f16x2*)(Aout + (size_t)v * 384 + 128 + 2 * l) =
      (f16x2){(_Float16)(aox * dvO), (_Float16)(aoy * dvO)};
}

// ---------------- batch norm ----------------
__global__ void k_bnfin(const float* __restrict__ bnAcc, const float* __restrict__ bnw,
                        const float* __restrict__ bnb, float* __restrict__ ss) {
  int c = threadIdx.x;
  float mu = bnAcc[c] * (1.f / (float)N_ENT);
  float var = bnAcc[128 + c] * (1.f / (float)N_ENT) - mu * mu;
  float sc = bnw[c] * rsqrtf(var + 1e-5f);
  ss[c] = sc; ss[128 + c] = bnb[c] - mu * sc;
}

__global__ void k_norm(float* __restrict__ out, const float* __restrict__ ss) {
  int i = blockIdx.x * 256 + threadIdx.x;
  float4* o = (float4*)out;
  float4 v = o[i];
  int c = (i & 31) * 4;
  v.x = v.x * ss[c]     + ss[128 + c];
  v.y = v.y * ss[c + 1] + ss[129 + c];
  v.z = v.z * ss[c + 2] + ss[130 + c];
  v.w = v.w * ss[c + 3] + ss[131 + c];
  o[i] = v;
}

extern "C" void kernel_launch(void* const* d_in, const int* in_sizes, int n_in,
                              void* d_out, int out_size, void* d_ws, size_t ws_size,
                              hipStream_t stream) {
  const float* x       = (const float*)d_in[0];
  const float* rel     = (const float*)d_in[1];
  const float* w_in    = (const float*)d_in[2];
  const float* w_out   = (const float*)d_in[3];
  const float* w_loop  = (const float*)d_in[4];
  const float* w_rel   = (const float*)d_in[5];
  const float* looprel = (const float*)d_in[6];
  const float* bias    = (const float*)d_in[7];
  const float* bnw     = (const float*)d_in[8];
  const float* bnb     = (const float*)d_in[9];
  const int*   ei      = (const int*)d_in[10];
  const int*   et      = (const int*)d_in[11];
  float* out = (float*)d_out;

  char* p = (char*)d_ws;
  auto alloc = [&](size_t bytes) -> void* {
    void* r = (void*)p;
    p += (bytes + 255) & ~(size_t)255;
    return r;
  };
  const size_t RECCAP8 = EHALF + NBUK * 776;    // dst splits (8B recs)
  const size_t RECCAP4 = EHALF + NBUK * 1808;   // src splits (4B recs)
  _Float16* Abuf  = (_Float16*)alloc((size_t)N_ENT * 384 * 2);
  _Float16* XinS  = (_Float16*)alloc((size_t)N_ENT * 128 * 2);
  _Float16* XoutS = (_Float16*)alloc((size_t)N_ENT * 128 * 2);
  _Float16* WT    = (_Float16*)alloc(128 * 384 * 2);
  _Float16* FtabT = (_Float16*)alloc(128 * 128 * 2);
  _Float16* RfL   = (_Float16*)alloc(501 * 64 * 4 * 2);
  float* Wstack   = (float*)alloc(384 * 128 * 4);
  float* Ftab     = (float*)alloc(128 * 128 * 4);
  float* Gtab     = (float*)alloc(128 * 128 * 4);
  float* Rf       = (float*)alloc(501 * 128 * 4);
  float* dinvIn   = (float*)alloc(N_ENT * 4);
  float* dinvOut  = (float*)alloc(N_ENT * 4);
  int*   btot     = (int*)alloc(4 * NBUK * 4);
  int*   bSI      = (int*)alloc(NBUK * 4);
  int*   gSI      = (int*)alloc(NBUK * 4);
  int*   bSO      = (int*)alloc(NBUK * 4);
  int*   gSO      = (int*)alloc(NBUK * 4);
  int*   bDI      = (int*)alloc(NBUK * 4);
  int*   gDI      = (int*)alloc(NBUK * 4);
  int*   cBI      = (int*)alloc((NBUK + 1) * 4);
  int*   bDO      = (int*)alloc(NBUK * 4);
  int*   gDO      = (int*)alloc(NBUK * 4);
  int*   cBO      = (int*)alloc((NBUK + 1) * 4);
  int*   offFineIn  = (int*)alloc((N_ENT + 1) * 4);
  int*   offFineOut = (int*)alloc((N_ENT + 1) * 4);
  unsigned* recSI = (unsigned*)alloc(RECCAP4 * 4);
  unsigned* recSO = (unsigned*)alloc(RECCAP4 * 4);
  uint2* recDI    = (uint2*)alloc(RECCAP8 * 8);
  uint2* recDO    = (uint2*)alloc(RECCAP8 * 8);
  uint2* csrIn    = (uint2*)alloc((size_t)EHALF * 8);
  uint2* csrOut   = (uint2*)alloc((size_t)EHALF * 8);
  float* bnAcc    = (float*)alloc(256 * 4);
  float* ss       = (float*)alloc(256 * 4);

  hipMemsetAsync(btot, 0, 4 * NBUK * 4, stream);
  hipMemsetAsync(bnAcc, 0, 256 * 4, stream);

  // tables + relation spectra + folded weight stack
  k_tabs<<<64, 256, 0, stream>>>(Ftab, Gtab, FtabT);
  k_dftrel<<<501, 128, 0, stream>>>(rel, looprel, Ftab, Rf);
  k_rpack<<<501, 64, 0, stream>>>(Rf, RfL);
  gemm128<<<2, 256, 0, stream>>>(Gtab, 128, w_in,   Wstack,             128, 128, 128);
  gemm128<<<2, 256, 0, stream>>>(Gtab, 128, w_out,  Wstack + 128 * 128, 128, 128, 128);
  gemm128<<<2, 256, 0, stream>>>(Gtab, 128, w_loop, Wstack + 256 * 128, 128, 128, 128);
  k_rotloop<<<64, 128, 0, stream>>>(Wstack + 256 * 128, Rf + 500 * 128);
  k_wt<<<192, 256, 0, stream>>>(Wstack, WT, 384);

  // coarse counts (LDS-privatized + 784 resident atomics) + 4 bucket scans
  k_ccount<<<CCB, 256, 0, stream>>>(ei, btot);
  k_bscan4<<<1, 256, 0, stream>>>(btot, bSI, gSI, bSO, gSO,
                                  bDI, gDI, cBI, bDO, gDO, cBO,
                                  offFineIn, offFineOut);

  // splits (write-amp-free): src-keyed (degrees) + dst-keyed (CSR)
  k_splitS<<<256, 256, 0, stream>>>(ei,         gSI, recSI);
  k_splitS<<<256, 256, 0, stream>>>(ei + EHALF, gSO, recSO);
  k_splitD<<<256, 256, 0, stream>>>(ei,         ei + 2 * EHALF, et,         gDI, recDI);
  k_splitD<<<256, 256, 0, stream>>>(ei + EHALF, ei + 3 * EHALF, et + EHALF, gDO, recDO);

  // degrees -> dinv (per-bucket LDS hist, dense writes)
  k_dhist<<<2 * NBUK, 512, 0, stream>>>(recSI, bSI, gSI, dinvIn, recSO, bSO, gSO, dinvOut);

  // Xf = rfft(x) via f16 MFMA; epilogue writes dinv-prescaled copies
  mgemm<128, 128, 1, false, float><<<(N_ENT + 255) / 256, 256, 0, stream>>>(
      x, 128, FtabT, (void*)(Abuf + 256), 384, N_ENT, nullptr, nullptr,
      dinvIn, dinvOut, XinS, XoutS);

  // fine CSR sort per bucket
  k_fsort<<<2 * NBUK, 512, 0, stream>>>(recDI, bDI, gDI, cBI, csrIn, offFineIn,
                                        recDO, bDO, gDO, cBO, csrOut, offFineOut);

  // frequency-domain aggregation, both directions interleaved
  k_agg<<<N_ENT / 4, 256, 0, stream>>>(XinS, XoutS, RfL,
                                       csrIn, offFineIn, csrOut, offFineOut,
                                       dinvIn, dinvOut, Abuf);

  // fused output GEMM (f16 MFMA): [c_in|c_out|Xf] @ Wstack + bias, BN stats
  mgemm<384, 192, 0, true, _Float16><<<(N_ENT + 255) / 256, 256, 0, stream>>>(
      Abuf, 384, WT, (void*)out, 128, N_ENT, bias, bnAcc,
      nullptr, nullptr, nullptr, nullptr);
  k_bnfin<<<1, 128, 0, stream>>>(bnAcc, bnw, bnb, ss);
  k_norm<<<(N_ENT * 128 / 4) / 256, 256, 0, stream>>>(out, ss);

  // rel_out = rel_embed @ w_rel (fp32)
  gemm128<<<(N_REL + 63) / 64, 256, 0, stream>>>(rel, 128, w_rel, out + (size_t)N_ENT * 128, 128, N_REL, 128);
}

// Round 7
// 359.702 us; speedup vs baseline: 1.3107x; 1.1613x over previous
//
#include <hip/hip_runtime.h>
#include <cmath>

#define N_ENT 100000
#define EHALF 1000000
#define N_REL 500
#define NBUK 196          // ceil(100000/512) coarse buckets (key>>9)
#define DPB 512           // entities per bucket
#define SCAP 7680         // src-record region capacity per bucket (4B recs)
#define DCAP 6656         // dst-record / csr region capacity per bucket (8B recs)

#ifndef M_PI
#define M_PI 3.14159265358979323846
#endif

typedef _Float16 f16x8 __attribute__((ext_vector_type(8)));
typedef _Float16 f16x4 __attribute__((ext_vector_type(4)));
typedef _Float16 f16x2 __attribute__((ext_vector_type(2)));
typedef float f32x4 __attribute__((ext_vector_type(4)));

union H16 { unsigned short u; _Float16 h; };

// ---------------- DFT tables ----------------
// Spectrum layout per row (128): slot0=Re(bin0), slot1=Re(bin64),
// slot 2f=Re(bin f), slot 2f+1=Im(bin f), f=1..63.
__global__ void k_tabs(float* __restrict__ Ftab, float* __restrict__ Gtab,
                       _Float16* __restrict__ FtabT) {
  int i = blockIdx.x * 256 + threadIdx.x;
  if (i >= 128 * 128) return;
  int n = i >> 7, s = i & 127;
  float fv, gv;
  if (s == 0) { fv = 1.f; gv = 1.f / 384.f; }
  else if (s == 1) { float sg = (n & 1) ? -1.f : 1.f; fv = sg; gv = sg / 384.f; }
  else {
    int f = s >> 1;
    double ang = 2.0 * M_PI * (double)((f * n) & 127) / 128.0;
    if (!(s & 1)) { double c = cos(ang); fv = (float)c; gv = (float)(c * (2.0 / 384.0)); }
    else { double sv = sin(ang); fv = (float)(-sv); gv = (float)(-sv * (2.0 / 384.0)); }
  }
  Ftab[n * 128 + s] = fv;
  Gtab[s * 128 + n] = gv;
  FtabT[s * 128 + n] = (_Float16)fv;
}

// Rf spectra + fused per-lane pack RfL[r][lane] = (A,B,C,D) f16:
// lane 0: (r0, 0, 0, r64); lane l>=1: (rx, ry, ry, -rx)
__global__ void k_dftrel(const float* __restrict__ rel, const float* __restrict__ looprel,
                         const float* __restrict__ Ftab, float* __restrict__ Rf,
                         _Float16* __restrict__ RfL) {
  __shared__ float sv[128];
  int r = blockIdx.x, s = threadIdx.x;
  const float* row = (r < N_REL) ? rel + (size_t)r * 128 : looprel;
  float acc = 0.f;
  for (int n = 0; n < 128; ++n) acc += row[n] * Ftab[n * 128 + s];
  Rf[(size_t)r * 128 + s] = acc;
  sv[s] = acc;
  __syncthreads();
  if (s < 64) {
    f16x4 o;
    if (s == 0) {
      o = (f16x4){(_Float16)sv[0], (_Float16)0.f, (_Float16)0.f, (_Float16)sv[1]};
    } else {
      float rx = sv[2 * s], ry = sv[2 * s + 1];
      o = (f16x4){(_Float16)rx, (_Float16)ry, (_Float16)ry, (_Float16)(-rx)};
    }
    ((f16x4*)RfL)[(size_t)r * 64 + s] = o;
  }
}

__global__ void k_rotloop(float* __restrict__ Wl, const float* __restrict__ Rfl) {
  int c = threadIdx.x;
  int f = blockIdx.x;
  if (f == 0) {
    Wl[c]       = Rfl[0] * Wl[c];
    Wl[128 + c] = Rfl[1] * Wl[128 + c];
  } else {
    float rr = Rfl[2 * f], ri = Rfl[2 * f + 1];
    float a = Wl[2 * f * 128 + c], b = Wl[(2 * f + 1) * 128 + c];
    Wl[2 * f * 128 + c]       = rr * a + ri * b;
    Wl[(2 * f + 1) * 128 + c] = ri * a - rr * b;
  }
}

__global__ void k_wt(const float* __restrict__ W, _Float16* __restrict__ WT, int K) {
  int i = blockIdx.x * 256 + threadIdx.x;
  if (i >= K * 128) return;
  int k = i >> 7, c = i & 127;
  WT[(size_t)c * K + k] = (_Float16)W[i];
}

// ---------------- fp32 GEMM (small preps + rel_out), N fixed = 128 ----------------
__global__ __launch_bounds__(256) void gemm128(
    const float* __restrict__ A, int lda,
    const float* __restrict__ B,
    float* __restrict__ C, int ldc,
    int M, int K) {
  __shared__ float As[64][64];
  __shared__ float Bs[64][128];
  const int t = threadIdx.x;
  const int m0 = blockIdx.x * 64;
  const int cg = t & 31;
  const int eg = t >> 5;
  float acc[8][4];
#pragma unroll
  for (int i = 0; i < 8; ++i)
#pragma unroll
    for (int j = 0; j < 4; ++j) acc[i][j] = 0.f;

  for (int k0 = 0; k0 < K; k0 += 64) {
#pragma unroll
    for (int p = 0; p < 4; ++p) {
      int idx = t + p * 256;
      int r = idx >> 4, c4 = idx & 15;
      int gr = m0 + r;
      float4 v = make_float4(0.f, 0.f, 0.f, 0.f);
      if (gr < M) v = *(const float4*)(A + (size_t)gr * lda + k0 + c4 * 4);
      *(float4*)&As[r][c4 * 4] = v;
    }
#pragma unroll
    for (int p = 0; p < 8; ++p) {
      int idx = t + p * 256;
      int r = idx >> 5, c4 = idx & 31;
      float4 v = *(const float4*)(B + (size_t)(k0 + r) * 128 + c4 * 4);
      *(float4*)&Bs[r][c4 * 4] = v;
    }
    __syncthreads();
#pragma unroll
    for (int k = 0; k < 64; ++k) {
      float4 bv = *(float4*)&Bs[k][cg * 4];
#pragma unroll
      for (int i = 0; i < 8; ++i) {
        float av = As[eg * 8 + i][k];
        acc[i][0] += av * bv.x; acc[i][1] += av * bv.y;
        acc[i][2] += av * bv.z; acc[i][3] += av * bv.w;
      }
    }
    __syncthreads();
  }
#pragma unroll
  for (int i = 0; i < 8; ++i) {
    int gr = m0 + eg * 8 + i;
    if (gr < M) {
      float4 v = make_float4(acc[i][0], acc[i][1], acc[i][2], acc[i][3]);
      *(float4*)(C + (size_t)gr * ldc + cg * 4) = v;
    }
  }
}

// ---------------- f16 MFMA GEMM, N=128 ----------------
__device__ inline f16x8 loadAfrag(const _Float16* A, size_t off) {
  return *(const f16x8*)(A + off);
}
__device__ inline f16x8 loadAfrag(const float* A, size_t off) {
  float4 u = *(const float4*)(A + off);
  float4 v = *(const float4*)(A + off + 4);
  return (f16x8){(_Float16)u.x, (_Float16)u.y, (_Float16)u.z, (_Float16)u.w,
                 (_Float16)v.x, (_Float16)v.y, (_Float16)v.z, (_Float16)v.w};
}

// MODE 0: fp32 C (+bias, +BN stats). MODE 1: f16 C.
template<int K, int KS, int MODE, bool BN, typename AT>
__global__ __launch_bounds__(256) void mgemm(
    const AT* __restrict__ A, int lda,
    const _Float16* __restrict__ BT,
    void* __restrict__ Cv, int ldc, int M,
    const float* __restrict__ bias, float* __restrict__ bnAcc) {
  __shared__ __align__(16) char lds[128 * KS * 2 + 4096];
  const int t = threadIdx.x;
  const int l = t & 63, w = t >> 6;
  const int col0 = l & 15, rg = l >> 4;
  const int rowbase = blockIdx.x * 256 + w * 64;
  const int sw = (col0 & 7) << 4;

  f32x4 acc[4][8];
  f32x4 zz = {0.f, 0.f, 0.f, 0.f};
#pragma unroll
  for (int a = 0; a < 4; ++a)
#pragma unroll
    for (int n = 0; n < 8; ++n) acc[a][n] = zz;

  for (int ks0 = 0; ks0 < K; ks0 += KS) {
    __syncthreads();
    const int CH = KS / 8;
    for (int u = t; u < 128 * CH; u += 256) {
      int col = u / CH, kc = u % CH;
      f16x8 vch = *(const f16x8*)(BT + (size_t)col * K + ks0 + kc * 8);
      *(f16x8*)(lds + col * (KS * 2) + ((kc * 16) ^ ((col & 7) << 4))) = vch;
    }
    __syncthreads();
#pragma unroll
    for (int ks = 0; ks < KS / 32; ++ks) {
      int kb = ks0 + ks * 32 + rg * 8;
      f16x8 af[4];
#pragma unroll
      for (int a = 0; a < 4; ++a) {
        int rb = rowbase + a * 16;
        if (rb < M) af[a] = loadAfrag(A, (size_t)(rb + col0) * lda + kb);
        else af[a] = (f16x8){0, 0, 0, 0, 0, 0, 0, 0};
      }
      int kc = ks * 4 + rg;
#pragma unroll
      for (int n = 0; n < 8; ++n) {
        f16x8 bf = *(const f16x8*)(lds + (n * 16 + col0) * (KS * 2) + ((kc * 16) ^ sw));
#pragma unroll
        for (int a = 0; a < 4; ++a)
          acc[a][n] = __builtin_amdgcn_mfma_f32_16x16x32_f16(af[a], bf, acc[a][n], 0, 0, 0);
      }
    }
  }

  if (MODE == 1) {
    _Float16* C = (_Float16*)Cv;
#pragma unroll
    for (int a = 0; a < 4; ++a) {
      int rb = rowbase + a * 16;
      if (rb >= M) continue;
#pragma unroll
      for (int r = 0; r < 4; ++r) {
        int row = rb + rg * 4 + r;
#pragma unroll
        for (int n = 0; n < 8; ++n) {
          int col = n * 16 + col0;
          C[(size_t)row * ldc + col] = (_Float16)acc[a][n][r];
        }
      }
    }
  } else {
    float* C = (float*)Cv;
    float sacc[8], qacc[8];
#pragma unroll
    for (int n = 0; n < 8; ++n) { sacc[n] = 0.f; qacc[n] = 0.f; }
#pragma unroll
    for (int a = 0; a < 4; ++a) {
      int rb = rowbase + a * 16;
      if (rb >= M) continue;
#pragma unroll
      for (int n = 0; n < 8; ++n) {
        int col = n * 16 + col0;
        float bi = bias ? bias[col] : 0.f;
#pragma unroll
        for (int r = 0; r < 4; ++r) {
          float val = acc[a][n][r] + bi;
          C[(size_t)(rb + rg * 4 + r) * ldc + col] = val;
          if (BN) { sacc[n] += val; qacc[n] += val * val; }
        }
      }
    }
    if (BN) {
      __syncthreads();
      float* Sb = (float*)lds;
      float* Qb = Sb + 512;
#pragma unroll
      for (int n = 0; n < 8; ++n) {
        float s = sacc[n], q = qacc[n];
        s += __shfl_xor(s, 16); s += __shfl_xor(s, 32);
        q += __shfl_xor(q, 16); q += __shfl_xor(q, 32);
        if (rg == 0) { Sb[w * 128 + n * 16 + col0] = s; Qb[w * 128 + n * 16 + col0] = q; }
      }
      __syncthreads();
      if (t < 128) {
        float s = Sb[t] + Sb[128 + t] + Sb[256 + t] + Sb[384 + t];
        float q = Qb[t] + Qb[128 + t] + Qb[256 + t] + Qb[384 + t];
        atomicAdd(&bnAcc[t], s);
        atomicAdd(&bnAcc[128 + t], q);
      }
    }
  }
}

// ---------------- edge preprocessing ----------------
// Region cursors: fixed per-bucket capacity regions (no global counts needed)
__global__ void k_init(int* __restrict__ gSI, int* __restrict__ gSO,
                       int* __restrict__ gDI, int* __restrict__ gDO) {
  int t = threadIdx.x;
  if (t < NBUK) {
    gSI[t] = t * SCAP; gSO[t] = t * SCAP;
    gDI[t] = t * DCAP; gDO[t] = t * DCAP;
  }
}

// src-keyed split (both dirs): 4B records, block-exclusive 32B chunks
__global__ __launch_bounds__(256) void k_splitS2(
    const int* __restrict__ ei,
    int* __restrict__ gSI, int* __restrict__ gSO,
    unsigned* __restrict__ recSI, unsigned* __restrict__ recSO) {
  __shared__ int bcnt[NBUK], cnt2[NBUK], base[NBUK], nn[NBUK];
  const int t = threadIdx.x;
  const int dir = blockIdx.x >> 8;
  const int blk = blockIdx.x & 255;
  const int* key = ei + (dir ? EHALF : 0);
  int* gcur = dir ? gSO : gSI;
  unsigned* rec = dir ? recSO : recSI;
  const int SPAN = 3907;
  int st = blk * SPAN;
  int en = min(st + SPAN, EHALF);
  if (t < NBUK) { bcnt[t] = 0; cnt2[t] = 0; }
  __syncthreads();
  unsigned rr[16]; int bb[16];
#pragma unroll
  for (int j = 0; j < 16; ++j) {
    int e = st + j * 256 + t;
    bb[j] = -1;
    if (e < en) {
      int s = key[e];
      rr[j] = (unsigned)(s & 511) | 0x80000000u;
      int b = s >> 9;
      bb[j] = b;
      atomicAdd(&bcnt[b], 1);
    }
  }
  __syncthreads();
  if (t < NBUK) {
    int n = bcnt[t]; nn[t] = n;
    base[t] = n ? atomicAdd(&gcur[t], (n + 7) & ~7) : 0;
  }
  __syncthreads();
#pragma unroll
  for (int j = 0; j < 16; ++j) {
    if (bb[j] >= 0) {
      int p = atomicAdd(&cnt2[bb[j]], 1);
      rec[(size_t)base[bb[j]] + p] = rr[j];
    }
  }
  __syncthreads();
  if (t < NBUK) {
    int n = nn[t];
    if (n & 7) {
      int pe = (n + 7) & ~7;
      for (int k = n; k < pe; ++k) rec[(size_t)base[t] + k] = 0u;
    }
  }
}

// per-bucket degree histogram -> dinv (dense writes, no global atomics)
__global__ __launch_bounds__(512) void k_dhist(
    const unsigned* __restrict__ recI, const int* __restrict__ gI,
    float* __restrict__ dinvIn,
    const unsigned* __restrict__ recO, const int* __restrict__ gO,
    float* __restrict__ dinvOut) {
  int b = blockIdx.x % NBUK;
  int dir = blockIdx.x / NBUK;
  const unsigned* rec = dir ? recO : recI;
  const int gs = b * SCAP;
  const int ge = (dir ? gO : gI)[b];
  float* dinv = dir ? dinvOut : dinvIn;
  __shared__ int h[DPB];
  int t = threadIdx.x;
  h[t] = 0;
  __syncthreads();
  for (int i = gs + t; i < ge; i += 512) {
    unsigned r = rec[i];
    if (r >> 31) atomicAdd(&h[r & 511], 1);
  }
  __syncthreads();
  int ent = b * 512 + t;
  if (ent < N_ENT) {
    int d = h[t];
    dinv[ent] = (d > 0) ? rsqrtf((float)d) : 0.f;
  }
}

// dst-keyed split (both dirs): 8B records {src|typ<<17, dstlo | normF16<<16}
__global__ __launch_bounds__(256) void k_splitD2(
    const int* __restrict__ ei, const int* __restrict__ et,
    const float* __restrict__ dinvIn, const float* __restrict__ dinvOut,
    int* __restrict__ gDI, int* __restrict__ gDO,
    uint2* __restrict__ recDI, uint2* __restrict__ recDO) {
  __shared__ int bcnt[NBUK], cnt2[NBUK], base[NBUK], nn[NBUK];
  const int t = threadIdx.x;
  const int dir = blockIdx.x >> 8;
  const int blk = blockIdx.x & 255;
  const int* srcA = ei + (dir ? EHALF : 0);
  const int* dstA = ei + (dir ? 3 * EHALF : 2 * EHALF);
  const int* typA = et + (dir ? EHALF : 0);
  const float* dv = dir ? dinvOut : dinvIn;
  int* gcur = dir ? gDO : gDI;
  uint2* rec = dir ? recDO : recDI;
  const int SPAN = 3907;
  int st = blk * SPAN;
  int en = min(st + SPAN, EHALF);
  if (t < NBUK) { bcnt[t] = 0; cnt2[t] = 0; }
  __syncthreads();
  unsigned w0[16], w1[16]; int bb[16];
#pragma unroll
  for (int j = 0; j < 16; ++j) {
    int e = st + j * 256 + t;
    bb[j] = -1;
    if (e < en) {
      int s = srcA[e], d = dstA[e], ty = typA[e];
      float nm = dv[s] * dv[d];
      H16 cv; cv.h = (_Float16)nm;
      w0[j] = (unsigned)s | ((unsigned)ty << 17);
      w1[j] = (unsigned)(d & 511) | ((unsigned)cv.u << 16);
      int b = d >> 9;
      bb[j] = b;
      atomicAdd(&bcnt[b], 1);
    }
  }
  __syncthreads();
  if (t < NBUK) {
    int n = bcnt[t]; nn[t] = n;
    base[t] = n ? atomicAdd(&gcur[t], (n + 3) & ~3) : 0;
  }
  __syncthreads();
#pragma unroll
  for (int j = 0; j < 16; ++j) {
    if (bb[j] >= 0) {
      int p = atomicAdd(&cnt2[bb[j]], 1);
      rec[(size_t)base[bb[j]] + p] = make_uint2(w0[j], w1[j]);
    }
  }
  __syncthreads();
  if (t < NBUK) {
    int n = nn[t];
    if (n & 3) {
      int pe = (n + 3) & ~3;
      for (int k = n; k < pe; ++k) rec[(size_t)base[t] + k] = make_uint2(0u, 0u);
    }
  }
}

// fine sort within bucket -> per-bucket-region CSR {xoff=src*768, typ|norm<<16}
// + per-entity {begin,end} int2. Valid record: norm bits != 0 (norm > 0 always).
__global__ __launch_bounds__(512) void k_fsort(
    const uint2* __restrict__ recDI, const int* __restrict__ gDI,
    uint2* __restrict__ csrIn, int2* __restrict__ beI,
    const uint2* __restrict__ recDO, const int* __restrict__ gDO,
    uint2* __restrict__ csrOut, int2* __restrict__ beO) {
  int b = blockIdx.x % NBUK;
  int dir = blockIdx.x / NBUK;
  const uint2* rec = dir ? recDO : recDI;
  const int gs = b * DCAP;
  const int ge = (dir ? gDO : gDI)[b];
  uint2* csr = dir ? csrOut : csrIn;
  int2* be = dir ? beO : beI;
  __shared__ int h[DPB], sc[DPB], c2[DPB];
  int t = threadIdx.x;
  h[t] = 0; c2[t] = 0;
  __syncthreads();
  for (int i = gs + t; i < ge; i += 512) {
    uint2 r = rec[i];
    if (r.y >> 16) atomicAdd(&h[r.y & 511], 1);
  }
  __syncthreads();
  sc[t] = h[t];
  __syncthreads();
  for (int o = 1; o < 512; o <<= 1) {
    int a = (t >= o) ? sc[t - o] : 0;
    __syncthreads();
    sc[t] += a;
    __syncthreads();
  }
  int excl = sc[t] - h[t];
  int ent = b * 512 + t;
  if (ent < N_ENT) be[ent] = make_int2(gs + excl, gs + excl + h[t]);
  __syncthreads();
  sc[t] = excl;
  __syncthreads();
  for (int i = gs + t; i < ge; i += 512) {
    uint2 r = rec[i];
    if (r.y >> 16) {
      int d = r.y & 511;
      int p = atomicAdd(&c2[d], 1);
      csr[(size_t)gs + sc[d] + p] =
          make_uint2(((r.x & 0x1FFFFu) * 3u) << 8,          // src*768
                     (r.x >> 17) | (r.y & 0xFFFF0000u));    // typ | norm<<16
    }
  }
}

// ---------------- frequency-domain edge aggregation (both directions) ----------------
// Xf gathered straight from Abuf rows (bytes +512..767); per-edge f16 norm.
__device__ inline void estep(uint2 q, const char* __restrict__ Xb,
                             const char* __restrict__ Rb,
                             unsigned lxc, unsigned lr, float& ax, float& ay) {
  f16x2 xv = *(const f16x2*)(Xb + q.x + lxc);
  f16x4 rv = *(const f16x4*)(Rb + ((q.y & 0x1FFu) << 9) + lr);
  H16 nu; nu.u = (unsigned short)(q.y >> 16);
  float nm = (float)nu.h;
  float px = fmaf((float)xv[0], (float)rv[0], (float)xv[1] * (float)rv[1]);
  float py = fmaf((float)xv[0], (float)rv[2], (float)xv[1] * (float)rv[3]);
  ax = fmaf(nm, px, ax);
  ay = fmaf(nm, py, ay);
}

__global__ __launch_bounds__(256) void k_agg(
    _Float16* __restrict__ Abuf, const _Float16* __restrict__ RfL,
    const uint2* __restrict__ csrIn, const int2* __restrict__ beI,
    const uint2* __restrict__ csrOut, const int2* __restrict__ beO) {
  const int w = threadIdx.x >> 6, l = threadIdx.x & 63;
  const int v = blockIdx.x * 4 + w;
  const char* Xb = (const char*)Abuf;
  const char* Rb = (const char*)RfL;
  const unsigned lxc = 512u + (unsigned)l * 4u;
  const unsigned lr = (unsigned)l * 8u;
  int2 bi = beI[v], bo = beO[v];
  int i = bi.x, ie = bi.y;
  int o = bo.x, oe = bo.y;
  float aix = 0.f, aiy = 0.f, aox = 0.f, aoy = 0.f;

  while (i + 4 <= ie && o + 4 <= oe) {
    uint2 a0 = csrIn[i], a1 = csrIn[i + 1], a2 = csrIn[i + 2], a3 = csrIn[i + 3];
    uint2 b0 = csrOut[o], b1 = csrOut[o + 1], b2 = csrOut[o + 2], b3 = csrOut[o + 3];
    estep(a0, Xb, Rb, lxc, lr, aix, aiy);
    estep(b0, Xb, Rb, lxc, lr, aox, aoy);
    estep(a1, Xb, Rb, lxc, lr, aix, aiy);
    estep(b1, Xb, Rb, lxc, lr, aox, aoy);
    estep(a2, Xb, Rb, lxc, lr, aix, aiy);
    estep(b2, Xb, Rb, lxc, lr, aox, aoy);
    estep(a3, Xb, Rb, lxc, lr, aix, aiy);
    estep(b3, Xb, Rb, lxc, lr, aox, aoy);
    i += 4; o += 4;
  }
  while (i + 4 <= ie) {
    uint2 a0 = csrIn[i], a1 = csrIn[i + 1], a2 = csrIn[i + 2], a3 = csrIn[i + 3];
    estep(a0, Xb, Rb, lxc, lr, aix, aiy);
    estep(a1, Xb, Rb, lxc, lr, aix, aiy);
    estep(a2, Xb, Rb, lxc, lr, aix, aiy);
    estep(a3, Xb, Rb, lxc, lr, aix, aiy);
    i += 4;
  }
  while (o + 4 <= oe) {
    uint2 b0 = csrOut[o], b1 = csrOut[o + 1], b2 = csrOut[o + 2], b3 = csrOut[o + 3];
    estep(b0, Xb, Rb, lxc, lr, aox, aoy);
    estep(b1, Xb, Rb, lxc, lr, aox, aoy);
    estep(b2, Xb, Rb, lxc, lr, aox, aoy);
    estep(b3, Xb, Rb, lxc, lr, aox, aoy);
    o += 4;
  }
  while (i < ie) { estep(csrIn[i], Xb, Rb, lxc, lr, aix, aiy); ++i; }
  while (o < oe) { estep(csrOut[o], Xb, Rb, lxc, lr, aox, aoy); ++o; }

  *(f16x2*)((char*)Abuf + (size_t)v * 768 + 4u * l) = (f16x2){(_Float16)aix, (_Float16)aiy};
  *(f16x2*)((char*)Abuf + (size_t)v * 768 + 256 + 4u * l) = (f16x2){(_Float16)aox, (_Float16)aoy};
}

// ---------------- batch norm ----------------
__global__ void k_bnfin(const float* __restrict__ bnAcc, const float* __restrict__ bnw,
                        const float* __restrict__ bnb, float* __restrict__ ss) {
  int c = threadIdx.x;
  float mu = bnAcc[c] * (1.f / (float)N_ENT);
  float var = bnAcc[128 + c] * (1.f / (float)N_ENT) - mu * mu;
  float sc = bnw[c] * rsqrtf(var + 1e-5f);
  ss[c] = sc; ss[128 + c] = bnb[c] - mu * sc;
}

__global__ void k_norm(float* __restrict__ out, const float* __restrict__ ss) {
  int i = blockIdx.x * 256 + threadIdx.x;
  float4* o = (float4*)out;
  float4 v = o[i];
  int c = (i & 31) * 4;
  v.x = v.x * ss[c]     + ss[128 + c];
  v.y = v.y * ss[c + 1] + ss[129 + c];
  v.z = v.z * ss[c + 2] + ss[130 + c];
  v.w = v.w * ss[c + 3] + ss[131 + c];
  o[i] = v;
}

extern "C" void kernel_launch(void* const* d_in, const int* in_sizes, int n_in,
                              void* d_out, int out_size, void* d_ws, size_t ws_size,
                              hipStream_t stream) {
  const float* x       = (const float*)d_in[0];
  const float* rel     = (const float*)d_in[1];
  const float* w_in    = (const float*)d_in[2];
  const float* w_out   = (const float*)d_in[3];
  const float* w_loop  = (const float*)d_in[4];
  const float* w_rel   = (const float*)d_in[5];
  const float* looprel = (const float*)d_in[6];
  const float* bias    = (const float*)d_in[7];
  const float* bnw     = (const float*)d_in[8];
  const float* bnb     = (const float*)d_in[9];
  const int*   ei      = (const int*)d_in[10];
  const int*   et      = (const int*)d_in[11];
  float* out = (float*)d_out;

  char* p = (char*)d_ws;
  auto alloc = [&](size_t bytes) -> void* {
    void* r = (void*)p;
    p += (bytes + 255) & ~(size_t)255;
    return r;
  };
  _Float16* Abuf  = (_Float16*)alloc((size_t)N_ENT * 384 * 2);
  _Float16* WT    = (_Float16*)alloc(128 * 384 * 2);
  _Float16* FtabT = (_Float16*)alloc(128 * 128 * 2);
  _Float16* RfL   = (_Float16*)alloc(501 * 64 * 4 * 2);
  float* Wstack   = (float*)alloc(384 * 128 * 4);
  float* Ftab     = (float*)alloc(128 * 128 * 4);
  float* Gtab     = (float*)alloc(128 * 128 * 4);
  float* Rf       = (float*)alloc(501 * 128 * 4);
  float* dinvIn   = (float*)alloc(N_ENT * 4);
  float* dinvOut  = (float*)alloc(N_ENT * 4);
  int*   gSI      = (int*)alloc(NBUK * 4);
  int*   gSO      = (int*)alloc(NBUK * 4);
  int*   gDI      = (int*)alloc(NBUK * 4);
  int*   gDO      = (int*)alloc(NBUK * 4);
  int2*  beI      = (int2*)alloc((size_t)N_ENT * 8);
  int2*  beO      = (int2*)alloc((size_t)N_ENT * 8);
  unsigned* recSI = (unsigned*)alloc((size_t)NBUK * SCAP * 4);
  unsigned* recSO = (unsigned*)alloc((size_t)NBUK * SCAP * 4);
  uint2* recDI    = (uint2*)alloc((size_t)NBUK * DCAP * 8);
  uint2* recDO    = (uint2*)alloc((size_t)NBUK * DCAP * 8);
  uint2* csrIn    = (uint2*)alloc((size_t)NBUK * DCAP * 8);
  uint2* csrOut   = (uint2*)alloc((size_t)NBUK * DCAP * 8);
  float* bnAcc    = (float*)alloc(256 * 4);
  float* ss       = (float*)alloc(256 * 4);

  hipMemsetAsync(bnAcc, 0, 256 * 4, stream);

  // tables + relation spectra (+ fused per-lane pack) + folded weight stack
  k_tabs<<<64, 256, 0, stream>>>(Ftab, Gtab, FtabT);
  k_dftrel<<<501, 128, 0, stream>>>(rel, looprel, Ftab, Rf, RfL);
  gemm128<<<2, 256, 0, stream>>>(Gtab, 128, w_in,   Wstack,             128, 128, 128);
  gemm128<<<2, 256, 0, stream>>>(Gtab, 128, w_out,  Wstack + 128 * 128, 128, 128, 128);
  gemm128<<<2, 256, 0, stream>>>(Gtab, 128, w_loop, Wstack + 256 * 128, 128, 128, 128);
  k_rotloop<<<64, 128, 0, stream>>>(Wstack + 256 * 128, Rf + 500 * 128);
  k_wt<<<192, 256, 0, stream>>>(Wstack, WT, 384);

  // Xf = rfft(x) via f16 MFMA into Abuf cols [256..384)
  mgemm<128, 128, 1, false, float><<<(N_ENT + 255) / 256, 256, 0, stream>>>(
      x, 128, FtabT, (void*)(Abuf + 256), 384, N_ENT, nullptr, nullptr);

  // fixed-capacity bucket regions: cursors init, then splits
  k_init<<<1, 256, 0, stream>>>(gSI, gSO, gDI, gDO);
  k_splitS2<<<512, 256, 0, stream>>>(ei, gSI, gSO, recSI, recSO);
  k_dhist<<<2 * NBUK, 512, 0, stream>>>(recSI, gSI, dinvIn, recSO, gSO, dinvOut);
  k_splitD2<<<512, 256, 0, stream>>>(ei, et, dinvIn, dinvOut, gDI, gDO, recDI, recDO);
  k_fsort<<<2 * NBUK, 512, 0, stream>>>(recDI, gDI, csrIn, beI, recDO, gDO, csrOut, beO);

  // frequency-domain aggregation (single Xf table, per-edge f16 norm)
  k_agg<<<N_ENT / 4, 256, 0, stream>>>(Abuf, RfL, csrIn, beI, csrOut, beO);

  // fused output GEMM (f16 MFMA): [c_in|c_out|Xf] @ Wstack + bias, BN stats
  mgemm<384, 192, 0, true, _Float16><<<(N_ENT + 255) / 256, 256, 0, stream>>>(
      Abuf, 384, WT, (void*)out, 128, N_ENT, bias, bnAcc);
  k_bnfin<<<1, 128, 0, stream>>>(bnAcc, bnw, bnb, ss);
  k_norm<<<(N_ENT * 128 / 4) / 256, 256, 0, stream>>>(out, ss);

  // rel_out = rel_embed @ w_rel (fp32)
  gemm128<<<(N_REL + 63) / 64, 256, 0, stream>>>(rel, 128, w_rel, out + (size_t)N_ENT * 128, 128, N_REL, 128);
}

// Round 8
// 337.114 us; speedup vs baseline: 1.3985x; 1.0670x over previous
//
#include <hip/hip_runtime.h>
#include <cmath>

#define N_ENT 100000
#define EHALF 1000000
#define N_REL 500
#define NBUK 196          // ceil(100000/512) coarse buckets (key>>9)
#define DPB 512           // entities per bucket
#define SCAP 7680         // src-record region capacity per bucket (4B recs)
#define DCAP 6656         // dst-record / csr region capacity per bucket (8B recs)

#ifndef M_PI
#define M_PI 3.14159265358979323846
#endif

typedef _Float16 f16x8 __attribute__((ext_vector_type(8)));
typedef _Float16 f16x4 __attribute__((ext_vector_type(4)));
typedef _Float16 f16x2 __attribute__((ext_vector_type(2)));
typedef float f32x4 __attribute__((ext_vector_type(4)));

union H16 { unsigned short u; _Float16 h; };
union HU32 { unsigned u; f16x2 h; };

// ---------------- DFT tables ----------------
// Spectrum layout per row (128): slot0=Re(bin0), slot1=Re(bin64),
// slot 2f=Re(bin f), slot 2f+1=Im(bin f), f=1..63.
__global__ void k_tabs(float* __restrict__ Ftab, float* __restrict__ Gtab,
                       _Float16* __restrict__ FtabT) {
  int i = blockIdx.x * 256 + threadIdx.x;
  if (i >= 128 * 128) return;
  int n = i >> 7, s = i & 127;
  float fv, gv;
  if (s == 0) { fv = 1.f; gv = 1.f / 384.f; }
  else if (s == 1) { float sg = (n & 1) ? -1.f : 1.f; fv = sg; gv = sg / 384.f; }
  else {
    int f = s >> 1;
    double ang = 2.0 * M_PI * (double)((f * n) & 127) / 128.0;
    if (!(s & 1)) { double c = cos(ang); fv = (float)c; gv = (float)(c * (2.0 / 384.0)); }
    else { double sv = sin(ang); fv = (float)(-sv); gv = (float)(-sv * (2.0 / 384.0)); }
  }
  Ftab[n * 128 + s] = fv;
  Gtab[s * 128 + n] = gv;
  FtabT[s * 128 + n] = (_Float16)fv;
}

// Rf spectra + fused per-lane pack RfL[r][lane] = (A,B,C,D) f16:
// lane 0: (r0, 0, 0, r64); lane l>=1: (rx, ry, ry, -rx)
__global__ void k_dftrel(const float* __restrict__ rel, const float* __restrict__ looprel,
                         const float* __restrict__ Ftab, float* __restrict__ Rf,
                         _Float16* __restrict__ RfL) {
  __shared__ float sv[128];
  int r = blockIdx.x, s = threadIdx.x;
  const float* row = (r < N_REL) ? rel + (size_t)r * 128 : looprel;
  float acc = 0.f;
  for (int n = 0; n < 128; ++n) acc += row[n] * Ftab[n * 128 + s];
  Rf[(size_t)r * 128 + s] = acc;
  sv[s] = acc;
  __syncthreads();
  if (s < 64) {
    f16x4 o;
    if (s == 0) {
      o = (f16x4){(_Float16)sv[0], (_Float16)0.f, (_Float16)0.f, (_Float16)sv[1]};
    } else {
      float rx = sv[2 * s], ry = sv[2 * s + 1];
      o = (f16x4){(_Float16)rx, (_Float16)ry, (_Float16)ry, (_Float16)(-rx)};
    }
    ((f16x4*)RfL)[(size_t)r * 64 + s] = o;
  }
}

// W transpose with fused loop-rel rotation on rows [256,384):
// WT[c][k] = (k<256) ? W[k][c] : rotated(W)[k][c]
__global__ void k_wt(const float* __restrict__ W, const float* __restrict__ Rfl,
                     _Float16* __restrict__ WT) {
  int i = blockIdx.x * 256 + threadIdx.x;
  if (i >= 384 * 128) return;
  int k = i >> 7, c = i & 127;
  float val;
  if (k < 256) {
    val = W[i];
  } else {
    int kk = k - 256;
    if (kk == 0)      val = Rfl[0] * W[i];
    else if (kk == 1) val = Rfl[1] * W[i];
    else {
      int f = kk >> 1;
      float rr = Rfl[2 * f], ri = Rfl[2 * f + 1];
      float a = W[(256 + 2 * f) * 128 + c];
      float b = W[(256 + 2 * f + 1) * 128 + c];
      val = (kk & 1) ? (ri * a - rr * b) : (rr * a + ri * b);
    }
  }
  WT[(size_t)c * 384 + k] = (_Float16)val;
}

// ---------------- fp32 GEMM body (preps + rel_out), N fixed = 128 ----------------
__device__ void gemm128_body(const float* __restrict__ A, int lda,
                             const float* __restrict__ B,
                             float* __restrict__ C, int ldc,
                             int M, int K, int m0) {
  __shared__ float As[64][64];
  __shared__ float Bs[64][128];
  const int t = threadIdx.x;
  const int cg = t & 31;
  const int eg = t >> 5;
  float acc[8][4];
#pragma unroll
  for (int i = 0; i < 8; ++i)
#pragma unroll
    for (int j = 0; j < 4; ++j) acc[i][j] = 0.f;

  for (int k0 = 0; k0 < K; k0 += 64) {
#pragma unroll
    for (int p = 0; p < 4; ++p) {
      int idx = t + p * 256;
      int r = idx >> 4, c4 = idx & 15;
      int gr = m0 + r;
      float4 v = make_float4(0.f, 0.f, 0.f, 0.f);
      if (gr < M) v = *(const float4*)(A + (size_t)gr * lda + k0 + c4 * 4);
      *(float4*)&As[r][c4 * 4] = v;
    }
#pragma unroll
    for (int p = 0; p < 8; ++p) {
      int idx = t + p * 256;
      int r = idx >> 5, c4 = idx & 31;
      float4 v = *(const float4*)(B + (size_t)(k0 + r) * 128 + c4 * 4);
      *(float4*)&Bs[r][c4 * 4] = v;
    }
    __syncthreads();
#pragma unroll
    for (int k = 0; k < 64; ++k) {
      float4 bv = *(float4*)&Bs[k][cg * 4];
#pragma unroll
      for (int i = 0; i < 8; ++i) {
        float av = As[eg * 8 + i][k];
        acc[i][0] += av * bv.x; acc[i][1] += av * bv.y;
        acc[i][2] += av * bv.z; acc[i][3] += av * bv.w;
      }
    }
    __syncthreads();
  }
#pragma unroll
  for (int i = 0; i < 8; ++i) {
    int gr = m0 + eg * 8 + i;
    if (gr < M) {
      float4 v = make_float4(acc[i][0], acc[i][1], acc[i][2], acc[i][3]);
      *(float4*)(C + (size_t)gr * ldc + cg * 4) = v;
    }
  }
}

__global__ __launch_bounds__(256) void gemm128(
    const float* __restrict__ A, int lda, const float* __restrict__ B,
    float* __restrict__ C, int ldc, int M, int K) {
  gemm128_body(A, lda, B, C, ldc, M, K, blockIdx.x * 64);
}

// batched prep: Wstack[w] = Gtab @ {w_in,w_out,w_loop}[w], grid 6
__global__ __launch_bounds__(256) void k_wprep(
    const float* __restrict__ Gtab, const float* __restrict__ w0,
    const float* __restrict__ w1, const float* __restrict__ w2,
    float* __restrict__ Wstack) {
  int which = blockIdx.x >> 1;
  const float* B = (which == 0) ? w0 : ((which == 1) ? w1 : w2);
  gemm128_body(Gtab, 128, B, Wstack + which * 128 * 128, 128, 128, 128,
               (blockIdx.x & 1) * 64);
}

// ---------------- f16 MFMA GEMM, N=128 ----------------
__device__ inline f16x8 loadAfrag(const _Float16* A, size_t off) {
  return *(const f16x8*)(A + off);
}
__device__ inline f16x8 loadAfrag(const float* A, size_t off) {
  float4 u = *(const float4*)(A + off);
  float4 v = *(const float4*)(A + off + 4);
  return (f16x8){(_Float16)u.x, (_Float16)u.y, (_Float16)u.z, (_Float16)u.w,
                 (_Float16)v.x, (_Float16)v.y, (_Float16)v.z, (_Float16)v.w};
}

// MODE 1: f16 C plain. MODE 2: f16 C + bias + BN stats (stats from fp32 accs).
template<int K, int KS, int MODE, typename AT>
__global__ __launch_bounds__(256) void mgemm(
    const AT* __restrict__ A, int lda,
    const _Float16* __restrict__ BT,
    _Float16* __restrict__ C, int ldc, int M,
    const float* __restrict__ bias, float* __restrict__ bnAcc) {
  __shared__ __align__(16) char lds[128 * KS * 2 + 4096];
  const int t = threadIdx.x;
  const int l = t & 63, w = t >> 6;
  const int col0 = l & 15, rg = l >> 4;
  const int rowbase = blockIdx.x * 256 + w * 64;
  const int sw = (col0 & 7) << 4;

  f32x4 acc[4][8];
  f32x4 zz = {0.f, 0.f, 0.f, 0.f};
#pragma unroll
  for (int a = 0; a < 4; ++a)
#pragma unroll
    for (int n = 0; n < 8; ++n) acc[a][n] = zz;

  for (int ks0 = 0; ks0 < K; ks0 += KS) {
    __syncthreads();
    const int CH = KS / 8;
    for (int u = t; u < 128 * CH; u += 256) {
      int col = u / CH, kc = u % CH;
      f16x8 vch = *(const f16x8*)(BT + (size_t)col * K + ks0 + kc * 8);
      *(f16x8*)(lds + col * (KS * 2) + ((kc * 16) ^ ((col & 7) << 4))) = vch;
    }
    __syncthreads();
#pragma unroll
    for (int ks = 0; ks < KS / 32; ++ks) {
      int kb = ks0 + ks * 32 + rg * 8;
      f16x8 af[4];
#pragma unroll
      for (int a = 0; a < 4; ++a) {
        int rb = rowbase + a * 16;
        if (rb < M) af[a] = loadAfrag(A, (size_t)(rb + col0) * lda + kb);
        else af[a] = (f16x8){0, 0, 0, 0, 0, 0, 0, 0};
      }
      int kc = ks * 4 + rg;
#pragma unroll
      for (int n = 0; n < 8; ++n) {
        f16x8 bf = *(const f16x8*)(lds + (n * 16 + col0) * (KS * 2) + ((kc * 16) ^ sw));
#pragma unroll
        for (int a = 0; a < 4; ++a)
          acc[a][n] = __builtin_amdgcn_mfma_f32_16x16x32_f16(af[a], bf, acc[a][n], 0, 0, 0);
      }
    }
  }

  if (MODE == 1) {
#pragma unroll
    for (int a = 0; a < 4; ++a) {
      int rb = rowbase + a * 16;
      if (rb >= M) continue;
#pragma unroll
      for (int r = 0; r < 4; ++r) {
        int row = rb + rg * 4 + r;
#pragma unroll
        for (int n = 0; n < 8; ++n) {
          int col = n * 16 + col0;
          C[(size_t)row * ldc + col] = (_Float16)acc[a][n][r];
        }
      }
    }
  } else {
    float sacc[8], qacc[8];
#pragma unroll
    for (int n = 0; n < 8; ++n) { sacc[n] = 0.f; qacc[n] = 0.f; }
#pragma unroll
    for (int a = 0; a < 4; ++a) {
      int rb = rowbase + a * 16;
      if (rb >= M) continue;
#pragma unroll
      for (int n = 0; n < 8; ++n) {
        int col = n * 16 + col0;
        float bi = bias[col];
#pragma unroll
        for (int r = 0; r < 4; ++r) {
          float val = acc[a][n][r] + bi;
          C[(size_t)(rb + rg * 4 + r) * ldc + col] = (_Float16)val;
          sacc[n] += val; qacc[n] += val * val;
        }
      }
    }
    __syncthreads();
    float* Sb = (float*)lds;
    float* Qb = Sb + 512;
#pragma unroll
    for (int n = 0; n < 8; ++n) {
      float s = sacc[n], q = qacc[n];
      s += __shfl_xor(s, 16); s += __shfl_xor(s, 32);
      q += __shfl_xor(q, 16); q += __shfl_xor(q, 32);
      if (rg == 0) { Sb[w * 128 + n * 16 + col0] = s; Qb[w * 128 + n * 16 + col0] = q; }
    }
    __syncthreads();
    if (t < 128) {
      float s = Sb[t] + Sb[128 + t] + Sb[256 + t] + Sb[384 + t];
      float q = Qb[t] + Qb[128 + t] + Qb[256 + t] + Qb[384 + t];
      atomicAdd(&bnAcc[t], s);
      atomicAdd(&bnAcc[128 + t], q);
    }
  }
}

// ---------------- edge preprocessing ----------------
// src-keyed split (both dirs): 4B records, block-exclusive 32B chunks.
// Cursors are RELATIVE (memset to 0); region base = bucket*SCAP.
__global__ __launch_bounds__(256) void k_splitS2(
    const int* __restrict__ ei,
    int* __restrict__ gSI, int* __restrict__ gSO,
    unsigned* __restrict__ recSI, unsigned* __restrict__ recSO) {
  __shared__ int bcnt[NBUK], cnt2[NBUK], base[NBUK], nn[NBUK];
  const int t = threadIdx.x;
  const int dir = blockIdx.x >> 8;
  const int blk = blockIdx.x & 255;
  const int* key = ei + (dir ? EHALF : 0);
  int* gcur = dir ? gSO : gSI;
  unsigned* rec = dir ? recSO : recSI;
  const int SPAN = 3907;
  int st = blk * SPAN;
  int en = min(st + SPAN, EHALF);
  if (t < NBUK) { bcnt[t] = 0; cnt2[t] = 0; }
  __syncthreads();
  unsigned rr[16]; int bb[16];
#pragma unroll
  for (int j = 0; j < 16; ++j) {
    int e = st + j * 256 + t;
    bb[j] = -1;
    if (e < en) {
      int s = key[e];
      rr[j] = (unsigned)(s & 511) | 0x80000000u;
      int b = s >> 9;
      bb[j] = b;
      atomicAdd(&bcnt[b], 1);
    }
  }
  __syncthreads();
  if (t < NBUK) {
    int n = bcnt[t]; nn[t] = n;
    base[t] = n ? (t * SCAP + atomicAdd(&gcur[t], (n + 7) & ~7)) : 0;
  }
  __syncthreads();
#pragma unroll
  for (int j = 0; j < 16; ++j) {
    if (bb[j] >= 0) {
      int p = atomicAdd(&cnt2[bb[j]], 1);
      rec[(size_t)base[bb[j]] + p] = rr[j];
    }
  }
  __syncthreads();
  if (t < NBUK) {
    int n = nn[t];
    if (n & 7) {
      int pe = (n + 7) & ~7;
      for (int k = n; k < pe; ++k) rec[(size_t)base[t] + k] = 0u;
    }
  }
}

// per-bucket degree histogram -> dinv (dense writes, no global atomics)
__global__ __launch_bounds__(512) void k_dhist(
    const unsigned* __restrict__ recI, const int* __restrict__ gI,
    float* __restrict__ dinvIn,
    const unsigned* __restrict__ recO, const int* __restrict__ gO,
    float* __restrict__ dinvOut) {
  int b = blockIdx.x % NBUK;
  int dir = blockIdx.x / NBUK;
  const unsigned* rec = dir ? recO : recI;
  const int gs = b * SCAP;
  const int ge = gs + (dir ? gO : gI)[b];
  float* dinv = dir ? dinvOut : dinvIn;
  __shared__ int h[DPB];
  int t = threadIdx.x;
  h[t] = 0;
  __syncthreads();
  for (int i = gs + t; i < ge; i += 512) {
    unsigned r = rec[i];
    if (r >> 31) atomicAdd(&h[r & 511], 1);
  }
  __syncthreads();
  int ent = b * 512 + t;
  if (ent < N_ENT) {
    int d = h[t];
    dinv[ent] = (d > 0) ? rsqrtf((float)d) : 0.f;
  }
}

// dst-keyed split (both dirs): 8B records {src|typ<<17, dstlo | normF16<<16}
__global__ __launch_bounds__(256) void k_splitD2(
    const int* __restrict__ ei, const int* __restrict__ et,
    const float* __restrict__ dinvIn, const float* __restrict__ dinvOut,
    int* __restrict__ gDI, int* __restrict__ gDO,
    uint2* __restrict__ recDI, uint2* __restrict__ recDO) {
  __shared__ int bcnt[NBUK], cnt2[NBUK], base[NBUK], nn[NBUK];
  const int t = threadIdx.x;
  const int dir = blockIdx.x >> 8;
  const int blk = blockIdx.x & 255;
  const int* srcA = ei + (dir ? EHALF : 0);
  const int* dstA = ei + (dir ? 3 * EHALF : 2 * EHALF);
  const int* typA = et + (dir ? EHALF : 0);
  const float* dv = dir ? dinvOut : dinvIn;
  int* gcur = dir ? gDO : gDI;
  uint2* rec = dir ? recDO : recDI;
  const int SPAN = 3907;
  int st = blk * SPAN;
  int en = min(st + SPAN, EHALF);
  if (t < NBUK) { bcnt[t] = 0; cnt2[t] = 0; }
  __syncthreads();
  unsigned w0[16], w1[16]; int bb[16];
#pragma unroll
  for (int j = 0; j < 16; ++j) {
    int e = st + j * 256 + t;
    bb[j] = -1;
    if (e < en) {
      int s = srcA[e], d = dstA[e], ty = typA[e];
      float nm = dv[s] * dv[d];
      H16 cv; cv.h = (_Float16)nm;
      w0[j] = (unsigned)s | ((unsigned)ty << 17);
      w1[j] = (unsigned)(d & 511) | ((unsigned)cv.u << 16);
      int b = d >> 9;
      bb[j] = b;
      atomicAdd(&bcnt[b], 1);
    }
  }
  __syncthreads();
  if (t < NBUK) {
    int n = bcnt[t]; nn[t] = n;
    base[t] = n ? (t * DCAP + atomicAdd(&gcur[t], (n + 3) & ~3)) : 0;
  }
  __syncthreads();
#pragma unroll
  for (int j = 0; j < 16; ++j) {
    if (bb[j] >= 0) {
      int p = atomicAdd(&cnt2[bb[j]], 1);
      rec[(size_t)base[bb[j]] + p] = make_uint2(w0[j], w1[j]);
    }
  }
  __syncthreads();
  if (t < NBUK) {
    int n = nn[t];
    if (n & 3) {
      int pe = (n + 3) & ~3;
      for (int k = n; k < pe; ++k) rec[(size_t)base[t] + k] = make_uint2(0u, 0u);
    }
  }
}

// fine sort within bucket -> per-bucket-region CSR {xoff=src*768, typ|norm<<16}
// + per-entity {begin,end} int2. Valid record: norm bits != 0.
__global__ __launch_bounds__(512) void k_fsort(
    const uint2* __restrict__ recDI, const int* __restrict__ gDI,
    uint2* __restrict__ csrIn, int2* __restrict__ beI,
    const uint2* __restrict__ recDO, const int* __restrict__ gDO,
    uint2* __restrict__ csrOut, int2* __restrict__ beO) {
  int b = blockIdx.x % NBUK;
  int dir = blockIdx.x / NBUK;
  const uint2* rec = dir ? recDO : recDI;
  const int gs = b * DCAP;
  const int ge = gs + (dir ? gDO : gDI)[b];
  uint2* csr = dir ? csrOut : csrIn;
  int2* be = dir ? beO : beI;
  __shared__ int h[DPB], sc[DPB], c2[DPB];
  int t = threadIdx.x;
  h[t] = 0; c2[t] = 0;
  __syncthreads();
  for (int i = gs + t; i < ge; i += 512) {
    uint2 r = rec[i];
    if (r.y >> 16) atomicAdd(&h[r.y & 511], 1);
  }
  __syncthreads();
  sc[t] = h[t];
  __syncthreads();
  for (int o = 1; o < 512; o <<= 1) {
    int a = (t >= o) ? sc[t - o] : 0;
    __syncthreads();
    sc[t] += a;
    __syncthreads();
  }
  int excl = sc[t] - h[t];
  int ent = b * 512 + t;
  if (ent < N_ENT) be[ent] = make_int2(gs + excl, gs + excl + h[t]);
  __syncthreads();
  sc[t] = excl;
  __syncthreads();
  for (int i = gs + t; i < ge; i += 512) {
    uint2 r = rec[i];
    if (r.y >> 16) {
      int d = r.y & 511;
      int p = atomicAdd(&c2[d], 1);
      csr[(size_t)gs + sc[d] + p] =
          make_uint2(((r.x & 0x1FFFFu) * 3u) << 8,          // src*768
                     (r.x >> 17) | (r.y & 0xFFFF0000u));    // typ | norm<<16
    }
  }
}

// ---------------- frequency-domain edge aggregation (both directions) ----------------
__device__ inline float dot2f(f16x2 a, f16x2 b, float c) {
#if __has_builtin(__builtin_amdgcn_fdot2)
  return __builtin_amdgcn_fdot2(a, b, c, false);
#else
  return fmaf((float)a[0], (float)b[0], fmaf((float)a[1], (float)b[1], c));
#endif
}

// Per edge: 1×4B X gather + 1×8B R load; pk_mul folds norm; 2×dot2 accumulate.
__device__ inline void estep(uint2 q, const char* __restrict__ Xb,
                             const char* __restrict__ Rb,
                             unsigned lxc, unsigned lr, float& ax, float& ay) {
  f16x2 xv = *(const f16x2*)(Xb + q.x + lxc);
  f16x4 rv = *(const f16x4*)(Rb + ((q.y & 0x1FFu) << 9) + lr);
  HU32 nm; nm.u = (q.y >> 16) | (q.y & 0xFFFF0000u);  // replicate norm bits
  f16x2 xs = xv * nm.h;                               // v_pk_mul_f16
  f16x2 rlo = {rv[0], rv[1]}, rhi = {rv[2], rv[3]};
  ax = dot2f(xs, rlo, ax);
  ay = dot2f(xs, rhi, ay);
}

__global__ __launch_bounds__(256) void k_agg(
    _Float16* __restrict__ Abuf, const _Float16* __restrict__ RfL,
    const uint2* __restrict__ csrIn, const int2* __restrict__ beI,
    const uint2* __restrict__ csrOut, const int2* __restrict__ beO) {
  const int w = threadIdx.x >> 6, l = threadIdx.x & 63;
  const int v = blockIdx.x * 4 + w;
  const char* Xb = (const char*)Abuf;
  const char* Rb = (const char*)RfL;
  const unsigned lxc = 512u + (unsigned)l * 4u;
  const unsigned lr = (unsigned)l * 8u;
  int2 bi = beI[v], bo = beO[v];
  int i = bi.x, ie = bi.y;
  int o = bo.x, oe = bo.y;
  float aix = 0.f, aiy = 0.f, aox = 0.f, aoy = 0.f;

  while (i + 4 <= ie && o + 4 <= oe) {
    uint2 a0 = csrIn[i], a1 = csrIn[i + 1], a2 = csrIn[i + 2], a3 = csrIn[i + 3];
    uint2 b0 = csrOut[o], b1 = csrOut[o + 1], b2 = csrOut[o + 2], b3 = csrOut[o + 3];
    estep(a0, Xb, Rb, lxc, lr, aix, aiy);
    estep(b0, Xb, Rb, lxc, lr, aox, aoy);
    estep(a1, Xb, Rb, lxc, lr, aix, aiy);
    estep(b1, Xb, Rb, lxc, lr, aox, aoy);
    estep(a2, Xb, Rb, lxc, lr, aix, aiy);
    estep(b2, Xb, Rb, lxc, lr, aox, aoy);
    estep(a3, Xb, Rb, lxc, lr, aix, aiy);
    estep(b3, Xb, Rb, lxc, lr, aox, aoy);
    i += 4; o += 4;
  }
  while (i + 4 <= ie) {
    uint2 a0 = csrIn[i], a1 = csrIn[i + 1], a2 = csrIn[i + 2], a3 = csrIn[i + 3];
    estep(a0, Xb, Rb, lxc, lr, aix, aiy);
    estep(a1, Xb, Rb, lxc, lr, aix, aiy);
    estep(a2, Xb, Rb, lxc, lr, aix, aiy);
    estep(a3, Xb, Rb, lxc, lr, aix, aiy);
    i += 4;
  }
  while (o + 4 <= oe) {
    uint2 b0 = csrOut[o], b1 = csrOut[o + 1], b2 = csrOut[o + 2], b3 = csrOut[o + 3];
    estep(b0, Xb, Rb, lxc, lr, aox, aoy);
    estep(b1, Xb, Rb, lxc, lr, aox, aoy);
    estep(b2, Xb, Rb, lxc, lr, aox, aoy);
    estep(b3, Xb, Rb, lxc, lr, aox, aoy);
    o += 4;
  }
  while (i < ie) { estep(csrIn[i], Xb, Rb, lxc, lr, aix, aiy); ++i; }
  while (o < oe) { estep(csrOut[o], Xb, Rb, lxc, lr, aox, aoy); ++o; }

  *(f16x2*)((char*)Abuf + (size_t)v * 768 + 4u * l) = (f16x2){(_Float16)aix, (_Float16)aiy};
  *(f16x2*)((char*)Abuf + (size_t)v * 768 + 256 + 4u * l) = (f16x2){(_Float16)aox, (_Float16)aoy};
}

// ---------------- batch norm ----------------
__global__ void k_bnfin(const float* __restrict__ bnAcc, const float* __restrict__ bnw,
                        const float* __restrict__ bnb, float* __restrict__ ss) {
  int c = threadIdx.x;
  float mu = bnAcc[c] * (1.f / (float)N_ENT);
  float var = bnAcc[128 + c] * (1.f / (float)N_ENT) - mu * mu;
  float sc = bnw[c] * rsqrtf(var + 1e-5f);
  ss[c] = sc; ss[128 + c] = bnb[c] - mu * sc;
}

// read f16 pre-BN tmp, write fp32 normalized output (8 elems/thread)
__global__ void k_norm(const _Float16* __restrict__ tmp, float* __restrict__ out,
                       const float* __restrict__ ss) {
  int i = blockIdx.x * 256 + threadIdx.x;  // N_ENT*128/8 threads
  f16x8 v = ((const f16x8*)tmp)[i];
  int cb = (i & 15) * 8;
  float4 o0, o1;
  o0.x = (float)v[0] * ss[cb]     + ss[128 + cb];
  o0.y = (float)v[1] * ss[cb + 1] + ss[129 + cb];
  o0.z = (float)v[2] * ss[cb + 2] + ss[130 + cb];
  o0.w = (float)v[3] * ss[cb + 3] + ss[131 + cb];
  o1.x = (float)v[4] * ss[cb + 4] + ss[132 + cb];
  o1.y = (float)v[5] * ss[cb + 5] + ss[133 + cb];
  o1.z = (float)v[6] * ss[cb + 6] + ss[134 + cb];
  o1.w = (float)v[7] * ss[cb + 7] + ss[135 + cb];
  ((float4*)out)[2 * i] = o0;
  ((float4*)out)[2 * i + 1] = o1;
}

extern "C" void kernel_launch(void* const* d_in, const int* in_sizes, int n_in,
                              void* d_out, int out_size, void* d_ws, size_t ws_size,
                              hipStream_t stream) {
  const float* x       = (const float*)d_in[0];
  const float* rel     = (const float*)d_in[1];
  const float* w_in    = (const float*)d_in[2];
  const float* w_out   = (const float*)d_in[3];
  const float* w_loop  = (const float*)d_in[4];
  const float* w_rel   = (const float*)d_in[5];
  const float* looprel = (const float*)d_in[6];
  const float* bias    = (const float*)d_in[7];
  const float* bnw     = (const float*)d_in[8];
  const float* bnb     = (const float*)d_in[9];
  const int*   ei      = (const int*)d_in[10];
  const int*   et      = (const int*)d_in[11];
  float* out = (float*)d_out;

  char* p = (char*)d_ws;
  auto alloc = [&](size_t bytes) -> void* {
    void* r = (void*)p;
    p += (bytes + 255) & ~(size_t)255;
    return r;
  };
  _Float16* Abuf  = (_Float16*)alloc((size_t)N_ENT * 384 * 2);
  _Float16* tmpC  = (_Float16*)alloc((size_t)N_ENT * 128 * 2);
  _Float16* WT    = (_Float16*)alloc(128 * 384 * 2);
  _Float16* FtabT = (_Float16*)alloc(128 * 128 * 2);
  _Float16* RfL   = (_Float16*)alloc(501 * 64 * 4 * 2);
  float* Wstack   = (float*)alloc(384 * 128 * 4);
  float* Ftab     = (float*)alloc(128 * 128 * 4);
  float* Gtab     = (float*)alloc(128 * 128 * 4);
  float* Rf       = (float*)alloc(501 * 128 * 4);
  float* dinvIn   = (float*)alloc(N_ENT * 4);
  float* dinvOut  = (float*)alloc(N_ENT * 4);
  int*   gcur     = (int*)alloc(4 * NBUK * 4);   // gSI|gSO|gDI|gDO (relative)
  int2*  beI      = (int2*)alloc((size_t)N_ENT * 8);
  int2*  beO      = (int2*)alloc((size_t)N_ENT * 8);
  unsigned* recSI = (unsigned*)alloc((size_t)NBUK * SCAP * 4);
  unsigned* recSO = (unsigned*)alloc((size_t)NBUK * SCAP * 4);
  uint2* recDI    = (uint2*)alloc((size_t)NBUK * DCAP * 8);
  uint2* recDO    = (uint2*)alloc((size_t)NBUK * DCAP * 8);
  uint2* csrIn    = (uint2*)alloc((size_t)NBUK * DCAP * 8);
  uint2* csrOut   = (uint2*)alloc((size_t)NBUK * DCAP * 8);
  float* bnAcc    = (float*)alloc(256 * 4);
  float* ss       = (float*)alloc(256 * 4);

  int* gSI = gcur;
  int* gSO = gcur + NBUK;
  int* gDI = gcur + 2 * NBUK;
  int* gDO = gcur + 3 * NBUK;

  hipMemsetAsync(gcur, 0, 4 * NBUK * 4, stream);
  hipMemsetAsync(bnAcc, 0, 256 * 4, stream);

  // tables + relation spectra (+ per-lane pack) + folded weight stack
  k_tabs<<<64, 256, 0, stream>>>(Ftab, Gtab, FtabT);
  k_dftrel<<<501, 128, 0, stream>>>(rel, looprel, Ftab, Rf, RfL);
  k_wprep<<<6, 256, 0, stream>>>(Gtab, w_in, w_out, w_loop, Wstack);
  k_wt<<<192, 256, 0, stream>>>(Wstack, Rf + 500 * 128, WT);

  // Xf = rfft(x) via f16 MFMA into Abuf cols [256..384)
  mgemm<128, 128, 1, float><<<(N_ENT + 255) / 256, 256, 0, stream>>>(
      x, 128, FtabT, Abuf + 256, 384, N_ENT, nullptr, nullptr);

  // splits (fixed-capacity regions, relative cursors)
  k_splitS2<<<512, 256, 0, stream>>>(ei, gSI, gSO, recSI, recSO);
  k_dhist<<<2 * NBUK, 512, 0, stream>>>(recSI, gSI, dinvIn, recSO, gSO, dinvOut);
  k_splitD2<<<512, 256, 0, stream>>>(ei, et, dinvIn, dinvOut, gDI, gDO, recDI, recDO);
  k_fsort<<<2 * NBUK, 512, 0, stream>>>(recDI, gDI, csrIn, beI, recDO, gDO, csrOut, beO);

  // frequency-domain aggregation (single Xf table, pk_mul + dot2 math)
  k_agg<<<N_ENT / 4, 256, 0, stream>>>(Abuf, RfL, csrIn, beI, csrOut, beO);

  // fused output GEMM (f16 MFMA): [c_in|c_out|Xf] @ Wstack + bias -> f16 tmp + BN stats
  mgemm<384, 192, 2, _Float16><<<(N_ENT + 255) / 256, 256, 0, stream>>>(
      Abuf, 384, WT, tmpC, 128, N_ENT, bias, bnAcc);
  k_bnfin<<<1, 128, 0, stream>>>(bnAcc, bnw, bnb, ss);
  k_norm<<<(N_ENT * 128 / 8) / 256, 256, 0, stream>>>(tmpC, out, ss);

  // rel_out = rel_embed @ w_rel (fp32)
  gemm128<<<(N_REL + 63) / 64, 256, 0, stream>>>(rel, 128, w_rel, out + (size_t)N_ENT * 128, 128, N_REL, 128);
}

// Round 9
// 324.861 us; speedup vs baseline: 1.4512x; 1.0377x over previous
//
#include <hip/hip_runtime.h>
#include <cmath>

#define N_ENT 100000
#define EHALF 1000000
#define N_REL 500
#define NBUK 196          // ceil(100000/512) coarse buckets (key>>9)
#define DPB 512           // entities per bucket
#define SCAP 7680         // src-record region capacity per bucket (4B recs)
#define DCAP 6656         // dst-record / csr region capacity per bucket (8B recs)
#define NSB 512           // split blocks
#define SPAN 1954         // ceil(EHALF/NSB)

#ifndef M_PI
#define M_PI 3.14159265358979323846
#endif

typedef _Float16 f16x8 __attribute__((ext_vector_type(8)));
typedef _Float16 f16x4 __attribute__((ext_vector_type(4)));
typedef _Float16 f16x2 __attribute__((ext_vector_type(2)));
typedef float f32x4 __attribute__((ext_vector_type(4)));

union H16 { unsigned short u; _Float16 h; };
union HU32 { unsigned u; f16x2 h; };

// ---------------- DFT tables ----------------
// Spectrum layout per row (128): slot0=Re(bin0), slot1=Re(bin64),
// slot 2f=Re(bin f), slot 2f+1=Im(bin f), f=1..63.
__global__ void k_tabs(float* __restrict__ Ftab, float* __restrict__ Gtab,
                       _Float16* __restrict__ FtabT) {
  int i = blockIdx.x * 256 + threadIdx.x;
  if (i >= 128 * 128) return;
  int n = i >> 7, s = i & 127;
  float fv, gv;
  if (s == 0) { fv = 1.f; gv = 1.f / 384.f; }
  else if (s == 1) { float sg = (n & 1) ? -1.f : 1.f; fv = sg; gv = sg / 384.f; }
  else {
    int f = s >> 1;
    double ang = 2.0 * M_PI * (double)((f * n) & 127) / 128.0;
    if (!(s & 1)) { double c = cos(ang); fv = (float)c; gv = (float)(c * (2.0 / 384.0)); }
    else { double sv = sin(ang); fv = (float)(-sv); gv = (float)(-sv * (2.0 / 384.0)); }
  }
  Ftab[n * 128 + s] = fv;
  Gtab[s * 128 + n] = gv;
  FtabT[s * 128 + n] = (_Float16)fv;
}

// Rf spectra + fused per-lane pack RfL[r][lane] = (A,B,C,D) f16:
// lane 0: (r0, 0, 0, r64); lane l>=1: (rx, ry, ry, -rx)
__global__ void k_dftrel(const float* __restrict__ rel, const float* __restrict__ looprel,
                         const float* __restrict__ Ftab, float* __restrict__ Rf,
                         _Float16* __restrict__ RfL) {
  __shared__ float sv[128];
  int r = blockIdx.x, s = threadIdx.x;
  const float* row = (r < N_REL) ? rel + (size_t)r * 128 : looprel;
  float acc = 0.f;
  for (int n = 0; n < 128; ++n) acc += row[n] * Ftab[n * 128 + s];
  Rf[(size_t)r * 128 + s] = acc;
  sv[s] = acc;
  __syncthreads();
  if (s < 64) {
    f16x4 o;
    if (s == 0) {
      o = (f16x4){(_Float16)sv[0], (_Float16)0.f, (_Float16)0.f, (_Float16)sv[1]};
    } else {
      float rx = sv[2 * s], ry = sv[2 * s + 1];
      o = (f16x4){(_Float16)rx, (_Float16)ry, (_Float16)ry, (_Float16)(-rx)};
    }
    ((f16x4*)RfL)[(size_t)r * 64 + s] = o;
  }
}

// W transpose with fused loop-rel rotation on rows [256,384)
__global__ void k_wt(const float* __restrict__ W, const float* __restrict__ Rfl,
                     _Float16* __restrict__ WT) {
  int i = blockIdx.x * 256 + threadIdx.x;
  if (i >= 384 * 128) return;
  int k = i >> 7, c = i & 127;
  float val;
  if (k < 256) {
    val = W[i];
  } else {
    int kk = k - 256;
    if (kk == 0)      val = Rfl[0] * W[i];
    else if (kk == 1) val = Rfl[1] * W[i];
    else {
      int f = kk >> 1;
      float rr = Rfl[2 * f], ri = Rfl[2 * f + 1];
      float a = W[(256 + 2 * f) * 128 + c];
      float b = W[(256 + 2 * f + 1) * 128 + c];
      val = (kk & 1) ? (ri * a - rr * b) : (rr * a + ri * b);
    }
  }
  WT[(size_t)c * 384 + k] = (_Float16)val;
}

// ---------------- fp32 GEMM body (preps + rel_out), N fixed = 128 ----------------
__device__ void gemm128_body(const float* __restrict__ A, int lda,
                             const float* __restrict__ B,
                             float* __restrict__ C, int ldc,
                             int M, int K, int m0) {
  __shared__ float As[64][64];
  __shared__ float Bs[64][128];
  const int t = threadIdx.x;
  const int cg = t & 31;
  const int eg = t >> 5;
  float acc[8][4];
#pragma unroll
  for (int i = 0; i < 8; ++i)
#pragma unroll
    for (int j = 0; j < 4; ++j) acc[i][j] = 0.f;

  for (int k0 = 0; k0 < K; k0 += 64) {
#pragma unroll
    for (int p = 0; p < 4; ++p) {
      int idx = t + p * 256;
      int r = idx >> 4, c4 = idx & 15;
      int gr = m0 + r;
      float4 v = make_float4(0.f, 0.f, 0.f, 0.f);
      if (gr < M) v = *(const float4*)(A + (size_t)gr * lda + k0 + c4 * 4);
      *(float4*)&As[r][c4 * 4] = v;
    }
#pragma unroll
    for (int p = 0; p < 8; ++p) {
      int idx = t + p * 256;
      int r = idx >> 5, c4 = idx & 31;
      float4 v = *(const float4*)(B + (size_t)(k0 + r) * 128 + c4 * 4);
      *(float4*)&Bs[r][c4 * 4] = v;
    }
    __syncthreads();
#pragma unroll
    for (int k = 0; k < 64; ++k) {
      float4 bv = *(float4*)&Bs[k][cg * 4];
#pragma unroll
      for (int i = 0; i < 8; ++i) {
        float av = As[eg * 8 + i][k];
        acc[i][0] += av * bv.x; acc[i][1] += av * bv.y;
        acc[i][2] += av * bv.z; acc[i][3] += av * bv.w;
      }
    }
    __syncthreads();
  }
#pragma unroll
  for (int i = 0; i < 8; ++i) {
    int gr = m0 + eg * 8 + i;
    if (gr < M) {
      float4 v = make_float4(acc[i][0], acc[i][1], acc[i][2], acc[i][3]);
      *(float4*)(C + (size_t)gr * ldc + cg * 4) = v;
    }
  }
}

__global__ __launch_bounds__(256) void gemm128(
    const float* __restrict__ A, int lda, const float* __restrict__ B,
    float* __restrict__ C, int ldc, int M, int K) {
  gemm128_body(A, lda, B, C, ldc, M, K, blockIdx.x * 64);
}

// batched prep: Wstack[w] = Gtab @ {w_in,w_out,w_loop}[w], grid 6
__global__ __launch_bounds__(256) void k_wprep(
    const float* __restrict__ Gtab, const float* __restrict__ w0,
    const float* __restrict__ w1, const float* __restrict__ w2,
    float* __restrict__ Wstack) {
  int which = blockIdx.x >> 1;
  const float* B = (which == 0) ? w0 : ((which == 1) ? w1 : w2);
  gemm128_body(Gtab, 128, B, Wstack + which * 128 * 128, 128, 128, 128,
               (blockIdx.x & 1) * 64);
}

// ---------------- f16 MFMA GEMM, N=128 ----------------
__device__ inline f16x8 loadAfrag(const _Float16* A, size_t off) {
  return *(const f16x8*)(A + off);
}
__device__ inline f16x8 loadAfrag(const float* A, size_t off) {
  float4 u = *(const float4*)(A + off);
  float4 v = *(const float4*)(A + off + 4);
  return (f16x8){(_Float16)u.x, (_Float16)u.y, (_Float16)u.z, (_Float16)u.w,
                 (_Float16)v.x, (_Float16)v.y, (_Float16)v.z, (_Float16)v.w};
}

// MODE 1: f16 C plain. MODE 2: f16 C + bias + BN stats (stats from fp32 accs).
template<int K, int KS, int MODE, typename AT>
__global__ __launch_bounds__(256) void mgemm(
    const AT* __restrict__ A, int lda,
    const _Float16* __restrict__ BT,
    _Float16* __restrict__ C, int ldc, int M,
    const float* __restrict__ bias, float* __restrict__ bnAcc) {
  __shared__ __align__(16) char lds[128 * KS * 2 + 4096];
  const int t = threadIdx.x;
  const int l = t & 63, w = t >> 6;
  const int col0 = l & 15, rg = l >> 4;
  const int rowbase = blockIdx.x * 256 + w * 64;
  const int sw = (col0 & 7) << 4;

  f32x4 acc[4][8];
  f32x4 zz = {0.f, 0.f, 0.f, 0.f};
#pragma unroll
  for (int a = 0; a < 4; ++a)
#pragma unroll
    for (int n = 0; n < 8; ++n) acc[a][n] = zz;

  for (int ks0 = 0; ks0 < K; ks0 += KS) {
    __syncthreads();
    const int CH = KS / 8;
    for (int u = t; u < 128 * CH; u += 256) {
      int col = u / CH, kc = u % CH;
      f16x8 vch = *(const f16x8*)(BT + (size_t)col * K + ks0 + kc * 8);
      *(f16x8*)(lds + col * (KS * 2) + ((kc * 16) ^ ((col & 7) << 4))) = vch;
    }
    __syncthreads();
#pragma unroll
    for (int ks = 0; ks < KS / 32; ++ks) {
      int kb = ks0 + ks * 32 + rg * 8;
      f16x8 af[4];
#pragma unroll
      for (int a = 0; a < 4; ++a) {
        int rb = rowbase + a * 16;
        if (rb < M) af[a] = loadAfrag(A, (size_t)(rb + col0) * lda + kb);
        else af[a] = (f16x8){0, 0, 0, 0, 0, 0, 0, 0};
      }
      int kc = ks * 4 + rg;
#pragma unroll
      for (int n = 0; n < 8; ++n) {
        f16x8 bf = *(const f16x8*)(lds + (n * 16 + col0) * (KS * 2) + ((kc * 16) ^ sw));
#pragma unroll
        for (int a = 0; a < 4; ++a)
          acc[a][n] = __builtin_amdgcn_mfma_f32_16x16x32_f16(af[a], bf, acc[a][n], 0, 0, 0);
      }
    }
  }

  if (MODE == 1) {
#pragma unroll
    for (int a = 0; a < 4; ++a) {
      int rb = rowbase + a * 16;
      if (rb >= M) continue;
#pragma unroll
      for (int r = 0; r < 4; ++r) {
        int row = rb + rg * 4 + r;
#pragma unroll
        for (int n = 0; n < 8; ++n) {
          int col = n * 16 + col0;
          C[(size_t)row * ldc + col] = (_Float16)acc[a][n][r];
        }
      }
    }
  } else {
    float sacc[8], qacc[8];
#pragma unroll
    for (int n = 0; n < 8; ++n) { sacc[n] = 0.f; qacc[n] = 0.f; }
#pragma unroll
    for (int a = 0; a < 4; ++a) {
      int rb = rowbase + a * 16;
      if (rb >= M) continue;
#pragma unroll
      for (int n = 0; n < 8; ++n) {
        int col = n * 16 + col0;
        float bi = bias[col];
#pragma unroll
        for (int r = 0; r < 4; ++r) {
          float val = acc[a][n][r] + bi;
          C[(size_t)(rb + rg * 4 + r) * ldc + col] = (_Float16)val;
          sacc[n] += val; qacc[n] += val * val;
        }
      }
    }
    __syncthreads();
    float* Sb = (float*)lds;
    float* Qb = Sb + 512;
#pragma unroll
    for (int n = 0; n < 8; ++n) {
      float s = sacc[n], q = qacc[n];
      s += __shfl_xor(s, 16); s += __shfl_xor(s, 32);
      q += __shfl_xor(q, 16); q += __shfl_xor(q, 32);
      if (rg == 0) { Sb[w * 128 + n * 16 + col0] = s; Qb[w * 128 + n * 16 + col0] = q; }
    }
    __syncthreads();
    if (t < 128) {
      float s = Sb[t] + Sb[128 + t] + Sb[256 + t] + Sb[384 + t];
      float q = Qb[t] + Qb[128 + t] + Qb[256 + t] + Qb[384 + t];
      atomicAdd(&bnAcc[t], s);
      atomicAdd(&bnAcc[128 + t], q);
    }
  }
}

// ---------------- edge preprocessing ----------------
// Merged split: 4 phases (srcIn, srcOut 4B recs; dstIn, dstOut 8B recs, no norm).
// Fixed-capacity per-bucket regions, relative cursors (memset 0).
__global__ __launch_bounds__(256) void k_split(
    const int* __restrict__ ei, const int* __restrict__ et,
    int* __restrict__ gcur,
    unsigned* __restrict__ recSI, unsigned* __restrict__ recSO,
    uint2* __restrict__ recDI, uint2* __restrict__ recDO) {
  __shared__ int bcnt[NBUK], cnt2[NBUK], base[NBUK], nn[NBUK];
  const int t = threadIdx.x;
  const int st = blockIdx.x * SPAN;
  const int en = min(st + SPAN, EHALF);

  // phases 0,1: src-keyed 4B records
  for (int ph = 0; ph < 2; ++ph) {
    const int* key = ei + (ph ? EHALF : 0);
    int* gc = gcur + ph * NBUK;
    unsigned* rec = ph ? recSO : recSI;
    if (t < NBUK) { bcnt[t] = 0; cnt2[t] = 0; }
    __syncthreads();
    unsigned rr[8]; int bb[8];
#pragma unroll
    for (int j = 0; j < 8; ++j) {
      int e = st + j * 256 + t;
      bb[j] = -1;
      if (e < en) {
        int s = key[e];
        rr[j] = (unsigned)(s & 511) | 0x80000000u;
        bb[j] = s >> 9;
        atomicAdd(&bcnt[bb[j]], 1);
      }
    }
    __syncthreads();
    if (t < NBUK) {
      int n = bcnt[t]; nn[t] = n;
      base[t] = n ? (t * SCAP + atomicAdd(&gc[t], (n + 7) & ~7)) : 0;
    }
    __syncthreads();
#pragma unroll
    for (int j = 0; j < 8; ++j) {
      if (bb[j] >= 0) {
        int p = atomicAdd(&cnt2[bb[j]], 1);
        rec[(size_t)base[bb[j]] + p] = rr[j];
      }
    }
    __syncthreads();
    if (t < NBUK) {
      int n = nn[t];
      if (n & 7) {
        int pe = (n + 7) & ~7;
        for (int k = n; k < pe; ++k) rec[(size_t)base[t] + k] = 0u;
      }
    }
    __syncthreads();
  }

  // phases 2,3: dst-keyed 8B records {src|typ<<17, dstlo|marker}
  for (int ph = 0; ph < 2; ++ph) {
    const int* srcA = ei + (ph ? EHALF : 0);
    const int* dstA = ei + (ph ? 3 * EHALF : 2 * EHALF);
    const int* typA = et + (ph ? EHALF : 0);
    int* gc = gcur + (2 + ph) * NBUK;
    uint2* rec = ph ? recDO : recDI;
    if (t < NBUK) { bcnt[t] = 0; cnt2[t] = 0; }
    __syncthreads();
    unsigned w0[8], w1[8]; int bb[8];
#pragma unroll
    for (int j = 0; j < 8; ++j) {
      int e = st + j * 256 + t;
      bb[j] = -1;
      if (e < en) {
        int s = srcA[e], d = dstA[e], ty = typA[e];
        w0[j] = (unsigned)s | ((unsigned)ty << 17);
        w1[j] = (unsigned)(d & 511) | 0x80000000u;
        bb[j] = d >> 9;
        atomicAdd(&bcnt[bb[j]], 1);
      }
    }
    __syncthreads();
    if (t < NBUK) {
      int n = bcnt[t]; nn[t] = n;
      base[t] = n ? (t * DCAP + atomicAdd(&gc[t], (n + 3) & ~3)) : 0;
    }
    __syncthreads();
#pragma unroll
    for (int j = 0; j < 8; ++j) {
      if (bb[j] >= 0) {
        int p = atomicAdd(&cnt2[bb[j]], 1);
        rec[(size_t)base[bb[j]] + p] = make_uint2(w0[j], w1[j]);
      }
    }
    __syncthreads();
    if (t < NBUK) {
      int n = nn[t];
      if (n & 3) {
        int pe = (n + 3) & ~3;
        for (int k = n; k < pe; ++k) rec[(size_t)base[t] + k] = make_uint2(0u, 0u);
      }
    }
    __syncthreads();
  }
}

// per-bucket degree histogram -> dinv (dense writes, no global atomics)
__global__ __launch_bounds__(512) void k_dhist(
    const unsigned* __restrict__ recI, const int* __restrict__ gI,
    float* __restrict__ dinvIn,
    const unsigned* __restrict__ recO, const int* __restrict__ gO,
    float* __restrict__ dinvOut) {
  int b = blockIdx.x % NBUK;
  int dir = blockIdx.x / NBUK;
  const unsigned* rec = dir ? recO : recI;
  const int gs = b * SCAP;
  const int ge = gs + (dir ? gO : gI)[b];
  float* dinv = dir ? dinvOut : dinvIn;
  __shared__ int h[DPB];
  int t = threadIdx.x;
  h[t] = 0;
  __syncthreads();
  for (int i = gs + t; i < ge; i += 512) {
    unsigned r = rec[i];
    if (r >> 31) atomicAdd(&h[r & 511], 1);
  }
  __syncthreads();
  int ent = b * 512 + t;
  if (ent < N_ENT) {
    int d = h[t];
    dinv[ent] = (d > 0) ? rsqrtf((float)d) : 0.f;
  }
}

// fine sort within bucket -> CSR {xoff=src*768, typ|normF16<<16} + {begin,end}.
// Norm computed here: dinv[src] (global gather) * dinv_lds[dst]. Zero-pads
// 8 records of bucket slack so k_agg batch reads never hit garbage.
__global__ __launch_bounds__(512) void k_fsort(
    const uint2* __restrict__ recDI, const int* __restrict__ gDI,
    uint2* __restrict__ csrIn, int2* __restrict__ beI,
    const uint2* __restrict__ recDO, const int* __restrict__ gDO,
    uint2* __restrict__ csrOut, int2* __restrict__ beO,
    const float* __restrict__ dinvIn, const float* __restrict__ dinvOut) {
  int b = blockIdx.x % NBUK;
  int dir = blockIdx.x / NBUK;
  const uint2* rec = dir ? recDO : recDI;
  const int gs = b * DCAP;
  const int ge = gs + (dir ? gDO : gDI)[b];
  const float* dinv = dir ? dinvOut : dinvIn;
  uint2* csr = dir ? csrOut : csrIn;
  int2* be = dir ? beO : beI;
  __shared__ int h[DPB], sc[DPB], c2[DPB];
  __shared__ float dl[DPB];
  __shared__ int totv;
  int t = threadIdx.x;
  int ent = b * 512 + t;
  h[t] = 0; c2[t] = 0;
  dl[t] = (ent < N_ENT) ? dinv[ent] : 0.f;
  __syncthreads();
  for (int i = gs + t; i < ge; i += 512) {
    uint2 r = rec[i];
    if (r.y >> 31) atomicAdd(&h[r.y & 511], 1);
  }
  __syncthreads();
  sc[t] = h[t];
  __syncthreads();
  for (int o = 1; o < 512; o <<= 1) {
    int a = (t >= o) ? sc[t - o] : 0;
    __syncthreads();
    sc[t] += a;
    __syncthreads();
  }
  int excl = sc[t] - h[t];
  if (t == 511) totv = sc[511];
  if (ent < N_ENT) be[ent] = make_int2(gs + excl, gs + excl + h[t]);
  __syncthreads();
  sc[t] = excl;
  __syncthreads();
  if (t < 8) csr[(size_t)gs + totv + t] = make_uint2(0u, 0u);
  for (int i = gs + t; i < ge; i += 512) {
    uint2 r = rec[i];
    if (r.y >> 31) {
      int d = r.y & 511;
      unsigned src = r.x & 0x1FFFFu;
      float nm = dinv[src] * dl[d];
      H16 cv; cv.h = (_Float16)nm;
      int p = atomicAdd(&c2[d], 1);
      csr[(size_t)gs + sc[d] + p] =
          make_uint2((src * 3u) << 8,                      // src*768 bytes
                     (r.x >> 17) | ((unsigned)cv.u << 16)); // typ | norm<<16
    }
  }
}

// ---------------- frequency-domain edge aggregation (both directions) ----------------
__device__ inline float dot2f(f16x2 a, f16x2 b, float c) {
#if __has_builtin(__builtin_amdgcn_fdot2)
  return __builtin_amdgcn_fdot2(a, b, c, false);
#else
  return fmaf((float)a[0], (float)b[0], fmaf((float)a[1], (float)b[1], c));
#endif
}

// 4-edge batch: load phase (4 csr rec + 4 X + 4 R in flight) then math phase.
// Overrun edges (idx >= end) are masked by zeroing norm bits (wave-uniform).
__device__ inline void b4load(const uint2* __restrict__ csr, int base,
                              const char* __restrict__ Xb, const char* __restrict__ Rb,
                              unsigned lxc, unsigned lr,
                              uint2 q[4], f16x2 xv[4], f16x4 rv[4]) {
#pragma unroll
  for (int j = 0; j < 4; ++j) q[j] = csr[base + j];
#pragma unroll
  for (int j = 0; j < 4; ++j) {
    xv[j] = *(const f16x2*)(Xb + q[j].x + lxc);
    rv[j] = *(const f16x4*)(Rb + ((q[j].y & 0x1FFu) << 9) + lr);
  }
}
__device__ inline void b4math(const uint2 q[4], int base, int end,
                              const f16x2 xv[4], const f16x4 rv[4],
                              float& ax, float& ay) {
#pragma unroll
  for (int j = 0; j < 4; ++j) {
    unsigned nb = (base + j < end) ? (q[j].y >> 16) : 0u;
    HU32 nm; nm.u = nb | (nb << 16);
    f16x2 xs = xv[j] * nm.h;
    ax = dot2f(xs, (f16x2){rv[j][0], rv[j][1]}, ax);
    ay = dot2f(xs, (f16x2){rv[j][2], rv[j][3]}, ay);
  }
}

__global__ __launch_bounds__(256) void k_agg(
    _Float16* __restrict__ Abuf, const _Float16* __restrict__ RfL,
    const uint2* __restrict__ csrIn, const int2* __restrict__ beI,
    const uint2* __restrict__ csrOut, const int2* __restrict__ beO) {
  const int w = threadIdx.x >> 6, l = threadIdx.x & 63;
  const int v = blockIdx.x * 4 + w;
  const char* Xb = (const char*)Abuf;
  const char* Rb = (const char*)RfL;
  const unsigned lxc = 512u + (unsigned)l * 4u;
  const unsigned lr = (unsigned)l * 8u;
  int2 bi = beI[v], bo = beO[v];
  int i  = __builtin_amdgcn_readfirstlane(bi.x);
  int ie = __builtin_amdgcn_readfirstlane(bi.y);
  int o  = __builtin_amdgcn_readfirstlane(bo.x);
  int oe = __builtin_amdgcn_readfirstlane(bo.y);
  int nbi = (ie - i + 3) >> 2;
  int nbo = (oe - o + 3) >> 2;
  float aix = 0.f, aiy = 0.f, aox = 0.f, aoy = 0.f;

  while (nbi > 0 && nbo > 0) {
    uint2 qa[4], qb[4]; f16x2 xa[4], xb[4]; f16x4 ra[4], rb[4];
    b4load(csrIn, i, Xb, Rb, lxc, lr, qa, xa, ra);
    b4load(csrOut, o, Xb, Rb, lxc, lr, qb, xb, rb);
    b4math(qa, i, ie, xa, ra, aix, aiy);
    b4math(qb, o, oe, xb, rb, aox, aoy);
    i += 4; o += 4; --nbi; --nbo;
  }
  while (nbi > 0) {
    uint2 qa[4]; f16x2 xa[4]; f16x4 ra[4];
    b4load(csrIn, i, Xb, Rb, lxc, lr, qa, xa, ra);
    b4math(qa, i, ie, xa, ra, aix, aiy);
    i += 4; --nbi;
  }
  while (nbo > 0) {
    uint2 qb[4]; f16x2 xb[4]; f16x4 rb[4];
    b4load(csrOut, o, Xb, Rb, lxc, lr, qb, xb, rb);
    b4math(qb, o, oe, xb, rb, aox, aoy);
    o += 4; --nbo;
  }

  *(f16x2*)((char*)Abuf + (size_t)v * 768 + 4u * l) = (f16x2){(_Float16)aix, (_Float16)aiy};
  *(f16x2*)((char*)Abuf + (size_t)v * 768 + 256 + 4u * l) = (f16x2){(_Float16)aox, (_Float16)aoy};
}

// ---------------- batch norm ----------------
__global__ void k_bnfin(const float* __restrict__ bnAcc, const float* __restrict__ bnw,
                        const float* __restrict__ bnb, float* __restrict__ ss) {
  int c = threadIdx.x;
  float mu = bnAcc[c] * (1.f / (float)N_ENT);
  float var = bnAcc[128 + c] * (1.f / (float)N_ENT) - mu * mu;
  float sc = bnw[c] * rsqrtf(var + 1e-5f);
  ss[c] = sc; ss[128 + c] = bnb[c] - mu * sc;
}

// read f16 pre-BN tmp, write fp32 normalized output (8 elems/thread)
__global__ void k_norm(const _Float16* __restrict__ tmp, float* __restrict__ out,
                       const float* __restrict__ ss) {
  int i = blockIdx.x * 256 + threadIdx.x;
  f16x8 v = ((const f16x8*)tmp)[i];
  int cb = (i & 15) * 8;
  float4 o0, o1;
  o0.x = (float)v[0] * ss[cb]     + ss[128 + cb];
  o0.y = (float)v[1] * ss[cb + 1] + ss[129 + cb];
  o0.z = (float)v[2] * ss[cb + 2] + ss[130 + cb];
  o0.w = (float)v[3] * ss[cb + 3] + ss[131 + cb];
  o1.x = (float)v[4] * ss[cb + 4] + ss[132 + cb];
  o1.y = (float)v[5] * ss[cb + 5] + ss[133 + cb];
  o1.z = (float)v[6] * ss[cb + 6] + ss[134 + cb];
  o1.w = (float)v[7] * ss[cb + 7] + ss[135 + cb];
  ((float4*)out)[2 * i] = o0;
  ((float4*)out)[2 * i + 1] = o1;
}

extern "C" void kernel_launch(void* const* d_in, const int* in_sizes, int n_in,
                              void* d_out, int out_size, void* d_ws, size_t ws_size,
                              hipStream_t stream) {
  const float* x       = (const float*)d_in[0];
  const float* rel     = (const float*)d_in[1];
  const float* w_in    = (const float*)d_in[2];
  const float* w_out   = (const float*)d_in[3];
  const float* w_loop  = (const float*)d_in[4];
  const float* w_rel   = (const float*)d_in[5];
  const float* looprel = (const float*)d_in[6];
  const float* bias    = (const float*)d_in[7];
  const float* bnw     = (const float*)d_in[8];
  const float* bnb     = (const float*)d_in[9];
  const int*   ei      = (const int*)d_in[10];
  const int*   et      = (const int*)d_in[11];
  float* out = (float*)d_out;

  char* p = (char*)d_ws;
  auto alloc = [&](size_t bytes) -> void* {
    void* r = (void*)p;
    p += (bytes + 255) & ~(size_t)255;
    return r;
  };
  _Float16* Abuf  = (_Float16*)alloc((size_t)N_ENT * 384 * 2);
  _Float16* tmpC  = (_Float16*)alloc((size_t)N_ENT * 128 * 2);
  _Float16* WT    = (_Float16*)alloc(128 * 384 * 2);
  _Float16* FtabT = (_Float16*)alloc(128 * 128 * 2);
  _Float16* RfL   = (_Float16*)alloc(501 * 64 * 4 * 2);
  float* Wstack   = (float*)alloc(384 * 128 * 4);
  float* Ftab     = (float*)alloc(128 * 128 * 4);
  float* Gtab     = (float*)alloc(128 * 128 * 4);
  float* Rf       = (float*)alloc(501 * 128 * 4);
  float* dinvIn   = (float*)alloc(N_ENT * 4);
  float* dinvOut  = (float*)alloc(N_ENT * 4);
  int*   gcur     = (int*)alloc(4 * NBUK * 4);   // gSI|gSO|gDI|gDO (relative)
  int2*  beI      = (int2*)alloc((size_t)N_ENT * 8);
  int2*  beO      = (int2*)alloc((size_t)N_ENT * 8);
  unsigned* recSI = (unsigned*)alloc((size_t)NBUK * SCAP * 4);
  unsigned* recSO = (unsigned*)alloc((size_t)NBUK * SCAP * 4);
  uint2* recDI    = (uint2*)alloc((size_t)NBUK * DCAP * 8);
  uint2* recDO    = (uint2*)alloc((size_t)NBUK * DCAP * 8);
  uint2* csrIn    = (uint2*)alloc((size_t)NBUK * DCAP * 8);
  uint2* csrOut   = (uint2*)alloc((size_t)NBUK * DCAP * 8);
  float* bnAcc    = (float*)alloc(256 * 4);
  float* ss       = (float*)alloc(256 * 4);

  int* gSI = gcur;
  int* gSO = gcur + NBUK;
  int* gDI = gcur + 2 * NBUK;
  int* gDO = gcur + 3 * NBUK;

  hipMemsetAsync(gcur, 0, 4 * NBUK * 4, stream);
  hipMemsetAsync(bnAcc, 0, 256 * 4, stream);

  // tables + relation spectra (+ per-lane pack) + folded weight stack
  k_tabs<<<64, 256, 0, stream>>>(Ftab, Gtab, FtabT);
  k_dftrel<<<501, 128, 0, stream>>>(rel, looprel, Ftab, Rf, RfL);
  k_wprep<<<6, 256, 0, stream>>>(Gtab, w_in, w_out, w_loop, Wstack);
  k_wt<<<192, 256, 0, stream>>>(Wstack, Rf + 500 * 128, WT);

  // Xf = rfft(x) via f16 MFMA into Abuf cols [256..384)
  mgemm<128, 128, 1, float><<<(N_ENT + 255) / 256, 256, 0, stream>>>(
      x, 128, FtabT, Abuf + 256, 384, N_ENT, nullptr, nullptr);

  // merged split (4 phases) -> degrees -> CSR (+norm fold, zero-padded slack)
  k_split<<<NSB, 256, 0, stream>>>(ei, et, gcur, recSI, recSO, recDI, recDO);
  k_dhist<<<2 * NBUK, 512, 0, stream>>>(recSI, gSI, dinvIn, recSO, gSO, dinvOut);
  k_fsort<<<2 * NBUK, 512, 0, stream>>>(recDI, gDI, csrIn, beI, recDO, gDO, csrOut, beO,
                                        dinvIn, dinvOut);

  // frequency-domain aggregation (predicated 4+4 batches, no serial tails)
  k_agg<<<N_ENT / 4, 256, 0, stream>>>(Abuf, RfL, csrIn, beI, csrOut, beO);

  // fused output GEMM (f16 MFMA): [c_in|c_out|Xf] @ Wstack + bias -> f16 tmp + BN stats
  mgemm<384, 192, 2, _Float16><<<(N_ENT + 255) / 256, 256, 0, stream>>>(
      Abuf, 384, WT, tmpC, 128, N_ENT, bias, bnAcc);
  k_bnfin<<<1, 128, 0, stream>>>(bnAcc, bnw, bnb, ss);
  k_norm<<<(N_ENT * 128 / 8) / 256, 256, 0, stream>>>(tmpC, out, ss);

  // rel_out = rel_embed @ w_rel (fp32)
  gemm128<<<(N_REL + 63) / 64, 256, 0, stream>>>(rel, 128, w_rel, out + (size_t)N_ENT * 128, 128, N_REL, 128);
}